// Round 14
// baseline (358.162 us; speedup 1.0000x reference)
//
#include <hip/hip_runtime.h>
#include <hip/hip_bf16.h>

#define N_NODES 50000
#define N_EDGES 500000
#define D 256
#define N_TOT 768      // 3 * D output cols of Wh
#define SCAN_N (3 * N_NODES)
#define SCAN_NBLK ((SCAN_N + 1023) / 1024)   // 147
#define NPASS 4                              // dst>>14: 50000 < 4*16384
#define NMB ((N_NODES + 255) / 256)          // 196 M-blocks

typedef __attribute__((ext_vector_type(8))) __bf16 bf16x8;
typedef __attribute__((ext_vector_type(4))) float f32x4;

__device__ __forceinline__ unsigned short f2bf(float f) {
    unsigned u = __builtin_bit_cast(unsigned, f);
    u += 0x7FFFu + ((u >> 16) & 1u);   // round-to-nearest-even
    return (unsigned short)(u >> 16);
}
__device__ __forceinline__ float bf2f(unsigned short h) {
    return __builtin_bit_cast(float, (unsigned)h << 16);
}
__device__ __forceinline__ void gload16(const unsigned short* g, __bf16* l) {
    __builtin_amdgcn_global_load_lds(
        (const __attribute__((address_space(1))) void*)g,
        (__attribute__((address_space(3))) void*)l, 16, 0, 0);
}

// ---------------- prep: feat->bf16 + W->bf16 transposed + edge COUNT (cnt pre-zeroed) ----------------
// WT layout: [768 outcols j=r*256+c][256 k], WT[j][k] = W_r[k][c]
__global__ void prep_kernel(const float* __restrict__ feat, unsigned short* __restrict__ fb,
                            const float* __restrict__ W0, const float* __restrict__ W1,
                            const float* __restrict__ W2, unsigned short* __restrict__ WT,
                            const int* __restrict__ d0, const int* __restrict__ d1,
                            const int* __restrict__ d2, int* __restrict__ cnt) {
    int i = blockIdx.x * blockDim.x + threadIdx.x;
    if (i < N_NODES * D / 4) {                       // 3.2M float4 slots, read-once -> NT load
        f32x4 v = __builtin_nontemporal_load((const f32x4*)feat + i);
        ushort4 pk;
        pk.x = f2bf(v.x); pk.y = f2bf(v.y); pk.z = f2bf(v.z); pk.w = f2bf(v.w);
        ((ushort4*)fb)[i] = pk;
    }
    if (i < N_TOT * D) {                             // 196608
        int j = i >> 8, k = i & 255;
        int r = j >> 8, c = j & 255;
        const float* W = (r == 0) ? W0 : (r == 1) ? W1 : W2;
        WT[i] = f2bf(W[k * D + c]);
    }
    if (i < 3 * N_EDGES) {                           // fused count (cnt zeroed by memset)
        int r = i / N_EDGES;
        int e = i - r * N_EDGES;
        const int* d = (r == 0) ? d0 : (r == 1) ? d1 : d2;
        atomicAdd(&cnt[r * N_NODES + d[e]], 1);
    }
}

// per-block exclusive scan; off/cur hold BLOCK-LOCAL offsets, bsum holds block totals
__global__ void scan1_kernel(const int* __restrict__ cnt, int* __restrict__ off,
                             int* __restrict__ cur, int* __restrict__ bsum) {
    __shared__ int wsum[16];
    int tid = threadIdx.x, lane = tid & 63, wid = tid >> 6;
    int i = blockIdx.x * 1024 + tid;
    int v = (i < SCAN_N) ? cnt[i] : 0;
    int x = v;
    #pragma unroll
    for (int d = 1; d < 64; d <<= 1) {
        int y = __shfl_up(x, d, 64);
        if (lane >= d) x += y;
    }
    if (lane == 63) wsum[wid] = x;
    __syncthreads();
    if (wid == 0 && lane < 16) {
        int s = wsum[lane];
        #pragma unroll
        for (int d = 1; d < 16; d <<= 1) {
            int y = __shfl_up(s, d, 64);
            if (lane >= d) s += y;
        }
        wsum[lane] = s;
    }
    __syncthreads();
    int wpre = wid ? wsum[wid - 1] : 0;
    int excl = x - v + wpre;
    if (i < SCAN_N) { off[i] = excl; cur[i] = excl; }
    if (tid == 1023) bsum[blockIdx.x] = x + wpre;
}

// exclusive scan of the 147 block sums (single block, in place)
__global__ void scan2_kernel(int* __restrict__ bsum) {
    __shared__ int wsum[16];
    int tid = threadIdx.x, lane = tid & 63, wid = tid >> 6;
    int v = (tid < SCAN_NBLK) ? bsum[tid] : 0;
    int x = v;
    #pragma unroll
    for (int d = 1; d < 64; d <<= 1) {
        int y = __shfl_up(x, d, 64);
        if (lane >= d) x += y;
    }
    if (lane == 63) wsum[wid] = x;
    __syncthreads();
    if (wid == 0 && lane < 16) {
        int s = wsum[lane];
        #pragma unroll
        for (int d = 1; d < 16; d <<= 1) {
            int y = __shfl_up(s, d, 64);
            if (lane >= d) s += y;
        }
        wsum[lane] = s;
    }
    __syncthreads();
    int wpre = wid ? wsum[wid - 1] : 0;
    if (tid < SCAN_NBLK) bsum[tid] = x - v + wpre;
}

// fill in NPASS dst-range passes (blockIdx.y = pass)
__global__ void fill_kernel(const int* __restrict__ s0, const int* __restrict__ d0,
                            const int* __restrict__ s1, const int* __restrict__ d1,
                            const int* __restrict__ s2, const int* __restrict__ d2,
                            int* __restrict__ cur, const int* __restrict__ bsum,
                            int* __restrict__ eidx) {
    int i = blockIdx.x * blockDim.x + threadIdx.x;
    if (i >= 3 * N_EDGES) return;
    int pass = blockIdx.y;
    int r = i / N_EDGES;
    int e = i - r * N_EDGES;
    const int* d = (r == 0) ? d0 : (r == 1) ? d1 : d2;
    int dd = d[e];
    if ((dd >> 14) != pass) return;
    const int* s = (r == 0) ? s0 : (r == 1) ? s1 : s2;
    int x = r * N_NODES + dd;
    int p = atomicAdd(&cur[x], 1) + bsum[x >> 10];
    eidx[p] = s[e];
}

// ---------------- GEMM-FIRST: Wh[n][r*256+c] = bf16( feat[n] @ W_r + b_r ) ----------------
// K = 256 -> only 4 K-steps of BK=64 (per-step drain ~4.7us is the empirical law).
// 2-buffer LDS (128 KB), fully unrolled, stage-ahead; swizzle slot^(row&7) both sides
// (linear LDS dest for global_load_lds + pre-swizzled global src + swizzled ds_read).
__global__ __launch_bounds__(512) void gemm_kernel(
    const unsigned short* __restrict__ A, const unsigned short* __restrict__ BT,
    const float* __restrict__ b0, const float* __restrict__ b1, const float* __restrict__ b2,
    unsigned short* __restrict__ Wh) {
    __shared__ __bf16 Asl[2][256][64];   // 2 x 32 KB
    __shared__ __bf16 Bsl[2][256][64];   // 2 x 32 KB
    int tid = threadIdx.x;
    int lane = tid & 63, w = tid >> 6;   // 8 waves
    int wr = w >> 2, wc = w & 3;         // wave tile: 128 rows x 64 cols
    int m0 = blockIdx.x * 256;
    int p = blockIdx.y;                  // relation panel 0..2
    const float* bp = (p == 0) ? b0 : (p == 1) ? b1 : b2;
    f32x4 acc[8][4] = {};

    auto stage = [&](int kt, int b) {
        #pragma unroll
        for (int i = 0; i < 4; ++i) {
            int slot = i * 512 + w * 64 + lane;        // 16B slots, wave-contiguous LDS
            int row = slot >> 3, ks = slot & 7;
            int g = ks ^ (row & 7);                    // pre-swizzled global k-slot
            int gm = m0 + row; if (gm >= N_NODES) gm = N_NODES - 1;
            gload16(A + (size_t)gm * D + kt * 64 + g * 8,
                    &Asl[b][0][0] + (size_t)slot * 8);
            gload16(BT + (size_t)(p * 256 + row) * D + kt * 64 + g * 8,
                    &Bsl[b][0][0] + (size_t)slot * 8);
        }
    };

    stage(0, 0);
    int rr = lane & 15, q = lane >> 4;
    #pragma unroll
    for (int kt = 0; kt < 4; ++kt) {
        asm volatile("s_waitcnt vmcnt(0)" ::: "memory");   // buf kt loads landed
        __builtin_amdgcn_s_barrier();
        int b = kt & 1;
        if (kt + 1 < 4) stage(kt + 1, b ^ 1);              // hide under compute below
        #pragma unroll
        for (int kh = 0; kh < 2; ++kh) {                   // two k-halves of BK=64
            bf16x8 af[8], bfr[4];
            #pragma unroll
            for (int mf = 0; mf < 8; ++mf) {
                int row = wr * 128 + mf * 16 + rr;
                int sl = (kh * 4 + q) ^ (row & 7);
                af[mf] = *(const bf16x8*)(&Asl[b][row][0] + sl * 8);
            }
            #pragma unroll
            for (int nf = 0; nf < 4; ++nf) {
                int row = wc * 64 + nf * 16 + rr;
                int sl = (kh * 4 + q) ^ (row & 7);
                bfr[nf] = *(const bf16x8*)(&Bsl[b][row][0] + sl * 8);
            }
            #pragma unroll
            for (int mf = 0; mf < 8; ++mf)
                #pragma unroll
                for (int nf = 0; nf < 4; ++nf)
                    acc[mf][nf] = __builtin_amdgcn_mfma_f32_16x16x32_bf16(af[mf], bfr[nf], acc[mf][nf], 0, 0, 0);
        }
        __builtin_amdgcn_s_barrier();                      // done reading buf b
    }

    // epilogue: +bias, cast bf16, NT store (Wh consumed much later from L3 -> don't
    // evict fb/WT from L2); C/D layout: col = lane&15, row = (lane>>4)*4 + reg
    #pragma unroll
    for (int mf = 0; mf < 8; ++mf) {
        #pragma unroll
        for (int nf = 0; nf < 4; ++nf) {
            int col = wc * 64 + nf * 16 + rr;
            float bb = bp[col];
            #pragma unroll
            for (int reg = 0; reg < 4; ++reg) {
                int row = m0 + wr * 128 + mf * 16 + q * 4 + reg;
                if (row < N_NODES)
                    __builtin_nontemporal_store(f2bf(acc[mf][nf][reg] + bb),
                                                Wh + (size_t)row * N_TOT + p * 256 + col);
            }
        }
    }
}

// ---------------- final: per-node gather Wh, mean per relation, sum, relu -> out (f32) ----------------
// One wave per node, all 3 relations; lane owns 4 channels (8B loads); 8-deep
// independent gathers. Bias is already inside Wh, so deg=0 relations contribute
// exactly 0 -- no masking needed.
__global__ void agg_kernel(const unsigned short* __restrict__ Wh, const int* __restrict__ off,
                           const int* __restrict__ cnt, const int* __restrict__ bsum,
                           const int* __restrict__ eidx, float* __restrict__ out) {
    int n = (blockIdx.x * blockDim.x + threadIdx.x) >> 6;
    int lane = threadIdx.x & 63;
    if (n >= N_NODES) return;

    int st3[3], dg3[3], e3[3];
    #pragma unroll
    for (int r = 0; r < 3; ++r) {
        int x = r * N_NODES + n;
        st3[r] = off[x] + bsum[x >> 10];
        dg3[r] = cnt[x];
    }
    #pragma unroll
    for (int r = 0; r < 3; ++r)                       // 3 head-loads in flight together
        e3[r] = (lane < dg3[r]) ? eidx[st3[r] + lane] : 0;

    float o0 = 0.f, o1 = 0.f, o2 = 0.f, o3 = 0.f;
    #pragma unroll
    for (int r = 0; r < 3; ++r) {
        const unsigned short* whl = Wh + r * 256 + lane * 4;
        int deg = dg3[r], start = st3[r];
        float4 acc = make_float4(0.f, 0.f, 0.f, 0.f);
        for (int base = 0; base < deg; base += 64) {
            int m = min(deg - base, 64);
            int e = base ? ((lane < m) ? eidx[start + base + lane] : 0) : e3[r];
            int j = 0;
            for (; j + 7 < m; j += 8) {
                int t0 = __shfl(e, j + 0), t1 = __shfl(e, j + 1), t2 = __shfl(e, j + 2), t3 = __shfl(e, j + 3);
                int t4 = __shfl(e, j + 4), t5 = __shfl(e, j + 5), t6 = __shfl(e, j + 6), t7 = __shfl(e, j + 7);
                ushort4 v0 = *(const ushort4*)(whl + (size_t)t0 * N_TOT);
                ushort4 v1 = *(const ushort4*)(whl + (size_t)t1 * N_TOT);
                ushort4 v2 = *(const ushort4*)(whl + (size_t)t2 * N_TOT);
                ushort4 v3 = *(const ushort4*)(whl + (size_t)t3 * N_TOT);
                ushort4 v4 = *(const ushort4*)(whl + (size_t)t4 * N_TOT);
                ushort4 v5 = *(const ushort4*)(whl + (size_t)t5 * N_TOT);
                ushort4 v6 = *(const ushort4*)(whl + (size_t)t6 * N_TOT);
                ushort4 v7 = *(const ushort4*)(whl + (size_t)t7 * N_TOT);
                acc.x += ((bf2f(v0.x) + bf2f(v1.x)) + (bf2f(v2.x) + bf2f(v3.x))) + ((bf2f(v4.x) + bf2f(v5.x)) + (bf2f(v6.x) + bf2f(v7.x)));
                acc.y += ((bf2f(v0.y) + bf2f(v1.y)) + (bf2f(v2.y) + bf2f(v3.y))) + ((bf2f(v4.y) + bf2f(v5.y)) + (bf2f(v6.y) + bf2f(v7.y)));
                acc.z += ((bf2f(v0.z) + bf2f(v1.z)) + (bf2f(v2.z) + bf2f(v3.z))) + ((bf2f(v4.z) + bf2f(v5.z)) + (bf2f(v6.z) + bf2f(v7.z)));
                acc.w += ((bf2f(v0.w) + bf2f(v1.w)) + (bf2f(v2.w) + bf2f(v3.w))) + ((bf2f(v4.w) + bf2f(v5.w)) + (bf2f(v6.w) + bf2f(v7.w)));
            }
            for (; j < m; ++j) {
                int t = __shfl(e, j);
                ushort4 v = *(const ushort4*)(whl + (size_t)t * N_TOT);
                acc.x += bf2f(v.x); acc.y += bf2f(v.y); acc.z += bf2f(v.z); acc.w += bf2f(v.w);
            }
        }
        float sc = (deg > 0) ? 1.0f / (float)deg : 0.0f;
        o0 += acc.x * sc; o1 += acc.y * sc; o2 += acc.z * sc; o3 += acc.w * sc;
    }
    f32x4 o;
    o.x = fmaxf(o0, 0.0f); o.y = fmaxf(o1, 0.0f);
    o.z = fmaxf(o2, 0.0f); o.w = fmaxf(o3, 0.0f);
    __builtin_nontemporal_store(o, (f32x4*)(out + (size_t)n * D + lane * 4));
}

extern "C" void kernel_launch(void* const* d_in, const int* in_sizes, int n_in,
                              void* d_out, int out_size, void* d_ws, size_t ws_size,
                              hipStream_t stream) {
    const float* feat = (const float*)d_in[0];
    const int* src0 = (const int*)d_in[1];
    const int* dst0 = (const int*)d_in[2];
    const int* src1 = (const int*)d_in[3];
    const int* dst1 = (const int*)d_in[4];
    const int* src2 = (const int*)d_in[5];
    const int* dst2 = (const int*)d_in[6];
    const float* W0 = (const float*)d_in[7];
    const float* b0 = (const float*)d_in[8];
    const float* W1 = (const float*)d_in[9];
    const float* b1 = (const float*)d_in[10];
    const float* W2 = (const float*)d_in[11];
    const float* b2 = (const float*)d_in[12];
    float* out = (float*)d_out;

    char* ws = (char*)d_ws;
    size_t o = 0;
    auto alloc = [&](size_t bytes) {
        size_t r = o;
        o += (bytes + 255) & ~(size_t)255;
        return r;
    };
    int* cnt            = (int*)(ws + alloc((size_t)SCAN_N * 4));
    int* off            = (int*)(ws + alloc((size_t)SCAN_N * 4));
    int* cur            = (int*)(ws + alloc((size_t)SCAN_N * 4));
    int* bsum           = (int*)(ws + alloc((size_t)SCAN_NBLK * 4));
    int* eidx           = (int*)(ws + alloc(3ull * N_EDGES * 4));
    unsigned short* WT  = (unsigned short*)(ws + alloc((size_t)N_TOT * D * 2));
    unsigned short* fb  = (unsigned short*)(ws + alloc((size_t)N_NODES * D * 2));
    unsigned short* Wh  = (unsigned short*)(ws + alloc((size_t)N_NODES * N_TOT * 2));

    (void)hipMemsetAsync(cnt, 0, (size_t)SCAN_N * 4, stream);
    prep_kernel<<<(N_NODES * D / 4 + 255) / 256, 256, 0, stream>>>(
        feat, fb, W0, W1, W2, WT, dst0, dst1, dst2, cnt);
    dim3 gg(NMB, 3);
    gemm_kernel<<<gg, 512, 0, stream>>>(fb, WT, b0, b1, b2, Wh);
    scan1_kernel<<<SCAN_NBLK, 1024, 0, stream>>>(cnt, off, cur, bsum);
    scan2_kernel<<<1, 1024, 0, stream>>>(bsum);
    dim3 fg((3 * N_EDGES + 255) / 256, NPASS);
    fill_kernel<<<fg, 256, 0, stream>>>(src0, dst0, src1, dst1, src2, dst2, cur, bsum, eidx);
    agg_kernel<<<(N_NODES * 64 + 255) / 256, 256, 0, stream>>>(Wh, off, cnt, bsum, eidx, out);
}

// Round 15
// 279.370 us; speedup vs baseline: 1.2820x; 1.2820x over previous
//
#include <hip/hip_runtime.h>
#include <hip/hip_bf16.h>

#define N_NODES 50000
#define N_EDGES 500000
#define D 256
#define N_TOT 768      // 3 * D output cols of Wh
#define SCAN_N (3 * N_NODES)
#define NPASS 4                              // dst>>14: 50000 < 4*16384
#define NMB ((N_NODES + 255) / 256)          // 196 M-blocks
#define SLOTS 32                             // fixed CSR slots/node (max deg ~25 for Poisson(10))
#define OVF_CAP 2048

typedef __attribute__((ext_vector_type(8))) __bf16 bf16x8;
typedef __attribute__((ext_vector_type(4))) float f32x4;

__device__ __forceinline__ unsigned short f2bf(float f) {
    unsigned u = __builtin_bit_cast(unsigned, f);
    u += 0x7FFFu + ((u >> 16) & 1u);   // round-to-nearest-even
    return (unsigned short)(u >> 16);
}
__device__ __forceinline__ float bf2f(unsigned short h) {
    return __builtin_bit_cast(float, (unsigned)h << 16);
}
__device__ __forceinline__ void gload16(const unsigned short* g, __bf16* l) {
    __builtin_amdgcn_global_load_lds(
        (const __attribute__((address_space(1))) void*)g,
        (__attribute__((address_space(3))) void*)l, 16, 0, 0);
}

// ---------------- prep: feat->bf16 + W->bf16 transposed (no counting any more) ----------------
// WT layout: [768 outcols j=r*256+c][256 k], WT[j][k] = W_r[k][c]
__global__ void prep_kernel(const float* __restrict__ feat, unsigned short* __restrict__ fb,
                            const float* __restrict__ W0, const float* __restrict__ W1,
                            const float* __restrict__ W2, unsigned short* __restrict__ WT) {
    int i = blockIdx.x * blockDim.x + threadIdx.x;
    if (i < N_NODES * D / 4) {                       // 3.2M float4 slots
        float4 v = ((const float4*)feat)[i];
        ushort4 pk;
        pk.x = f2bf(v.x); pk.y = f2bf(v.y); pk.z = f2bf(v.z); pk.w = f2bf(v.w);
        ((ushort4*)fb)[i] = pk;
    }
    if (i < N_TOT * D) {                             // 196608
        int j = i >> 8, k = i & 255;
        int r = j >> 8, c = j & 255;
        const float* W = (r == 0) ? W0 : (r == 1) ? W1 : W2;
        WT[i] = f2bf(W[k * D + c]);
    }
}

// ---------------- fill: fixed-stride bucket CSR, no scan needed ----------------
// rank = atomicAdd(cur[x]); eidx[x*SLOTS+rank] = src. cur[x] ends as deg.
// NPASS dst-range passes confine the scatter window for L2 merge.
// Overflow (rank >= SLOTS, provably cold for this input) goes to an exact side list.
__global__ void fill_kernel(const int* __restrict__ s0, const int* __restrict__ d0,
                            const int* __restrict__ s1, const int* __restrict__ d1,
                            const int* __restrict__ s2, const int* __restrict__ d2,
                            int* __restrict__ cur, int* __restrict__ eidx,
                            int* __restrict__ ovfc, int* __restrict__ ovf) {
    int i = blockIdx.x * blockDim.x + threadIdx.x;
    if (i >= 3 * N_EDGES) return;
    int pass = blockIdx.y;
    int r = i / N_EDGES;
    int e = i - r * N_EDGES;
    const int* d = (r == 0) ? d0 : (r == 1) ? d1 : d2;
    int dd = d[e];
    if ((dd >> 14) != pass) return;
    const int* s = (r == 0) ? s0 : (r == 1) ? s1 : s2;
    int x = r * N_NODES + dd;
    int rank = atomicAdd(&cur[x], 1);
    if (rank < SLOTS) {
        eidx[(size_t)x * SLOTS + rank] = s[e];
    } else {
        int op = atomicAdd(ovfc, 1);
        if (op < OVF_CAP) { ovf[2 * op] = x; ovf[2 * op + 1] = s[e]; }
    }
}

// ---------------- GEMM-FIRST: Wh[n][r*256+c] = bf16( feat[n] @ W_r + b_r ) ----------------
// K = 256 -> only 4 K-steps of BK=64 (per-step drain ~4.7us is the empirical law).
// 2-buffer LDS (128 KB), fully unrolled, stage-ahead; swizzle slot^(row&7) both sides
// (linear LDS dest for global_load_lds + pre-swizzled global src + swizzled ds_read).
__global__ __launch_bounds__(512) void gemm_kernel(
    const unsigned short* __restrict__ A, const unsigned short* __restrict__ BT,
    const float* __restrict__ b0, const float* __restrict__ b1, const float* __restrict__ b2,
    unsigned short* __restrict__ Wh) {
    __shared__ __bf16 Asl[2][256][64];   // 2 x 32 KB
    __shared__ __bf16 Bsl[2][256][64];   // 2 x 32 KB
    int tid = threadIdx.x;
    int lane = tid & 63, w = tid >> 6;   // 8 waves
    int wr = w >> 2, wc = w & 3;         // wave tile: 128 rows x 64 cols
    int m0 = blockIdx.x * 256;
    int p = blockIdx.y;                  // relation panel 0..2
    const float* bp = (p == 0) ? b0 : (p == 1) ? b1 : b2;
    f32x4 acc[8][4] = {};

    auto stage = [&](int kt, int b) {
        #pragma unroll
        for (int i = 0; i < 4; ++i) {
            int slot = i * 512 + w * 64 + lane;        // 16B slots, wave-contiguous LDS
            int row = slot >> 3, ks = slot & 7;
            int g = ks ^ (row & 7);                    // pre-swizzled global k-slot
            int gm = m0 + row; if (gm >= N_NODES) gm = N_NODES - 1;
            gload16(A + (size_t)gm * D + kt * 64 + g * 8,
                    &Asl[b][0][0] + (size_t)slot * 8);
            gload16(BT + (size_t)(p * 256 + row) * D + kt * 64 + g * 8,
                    &Bsl[b][0][0] + (size_t)slot * 8);
        }
    };

    stage(0, 0);
    int rr = lane & 15, q = lane >> 4;
    #pragma unroll
    for (int kt = 0; kt < 4; ++kt) {
        asm volatile("s_waitcnt vmcnt(0)" ::: "memory");   // buf kt loads landed
        __builtin_amdgcn_s_barrier();
        int b = kt & 1;
        if (kt + 1 < 4) stage(kt + 1, b ^ 1);              // hide under compute below
        #pragma unroll
        for (int kh = 0; kh < 2; ++kh) {                   // two k-halves of BK=64
            bf16x8 af[8], bfr[4];
            #pragma unroll
            for (int mf = 0; mf < 8; ++mf) {
                int row = wr * 128 + mf * 16 + rr;
                int sl = (kh * 4 + q) ^ (row & 7);
                af[mf] = *(const bf16x8*)(&Asl[b][row][0] + sl * 8);
            }
            #pragma unroll
            for (int nf = 0; nf < 4; ++nf) {
                int row = wc * 64 + nf * 16 + rr;
                int sl = (kh * 4 + q) ^ (row & 7);
                bfr[nf] = *(const bf16x8*)(&Bsl[b][row][0] + sl * 8);
            }
            #pragma unroll
            for (int mf = 0; mf < 8; ++mf)
                #pragma unroll
                for (int nf = 0; nf < 4; ++nf)
                    acc[mf][nf] = __builtin_amdgcn_mfma_f32_16x16x32_bf16(af[mf], bfr[nf], acc[mf][nf], 0, 0, 0);
        }
        __builtin_amdgcn_s_barrier();                      // done reading buf b
    }

    // epilogue: +bias, cast bf16; C/D layout: col = lane&15, row = (lane>>4)*4 + reg
    #pragma unroll
    for (int mf = 0; mf < 8; ++mf) {
        #pragma unroll
        for (int nf = 0; nf < 4; ++nf) {
            int col = wc * 64 + nf * 16 + rr;
            float bb = bp[col];
            #pragma unroll
            for (int reg = 0; reg < 4; ++reg) {
                int row = m0 + wr * 128 + mf * 16 + q * 4 + reg;
                if (row < N_NODES)
                    Wh[(size_t)row * N_TOT + p * 256 + col] = f2bf(acc[mf][nf][reg] + bb);
            }
        }
    }
}

// ---------------- final: per-node gather Wh, mean per relation, sum, relu -> out (f32) ----------------
// One wave per node, all 3 relations; lane owns 4 channels (8B loads); 8-deep
// independent gathers. Bias already inside Wh -> deg=0 relations contribute exactly 0.
__global__ void agg_kernel(const unsigned short* __restrict__ Wh, const int* __restrict__ cur,
                           const int* __restrict__ eidx, const int* __restrict__ ovfc,
                           const int* __restrict__ ovf, float* __restrict__ out) {
    int n = (blockIdx.x * blockDim.x + threadIdx.x) >> 6;
    int lane = threadIdx.x & 63;
    if (n >= N_NODES) return;

    int dg3[3], e3[3];
    #pragma unroll
    for (int r = 0; r < 3; ++r)
        dg3[r] = cur[r * N_NODES + n];
    #pragma unroll
    for (int r = 0; r < 3; ++r) {                     // 3 head-loads in flight together
        int x = r * N_NODES + n;
        e3[r] = (lane < min(dg3[r], SLOTS)) ? eidx[(size_t)x * SLOTS + lane] : 0;
    }

    float o0 = 0.f, o1 = 0.f, o2 = 0.f, o3 = 0.f;
    #pragma unroll
    for (int r = 0; r < 3; ++r) {
        const unsigned short* whl = Wh + r * 256 + lane * 4;
        int deg = dg3[r];
        int m = min(deg, SLOTS);
        int e = e3[r];
        float4 acc = make_float4(0.f, 0.f, 0.f, 0.f);
        int j = 0;
        for (; j + 7 < m; j += 8) {
            int t0 = __shfl(e, j + 0), t1 = __shfl(e, j + 1), t2 = __shfl(e, j + 2), t3 = __shfl(e, j + 3);
            int t4 = __shfl(e, j + 4), t5 = __shfl(e, j + 5), t6 = __shfl(e, j + 6), t7 = __shfl(e, j + 7);
            ushort4 v0 = *(const ushort4*)(whl + (size_t)t0 * N_TOT);
            ushort4 v1 = *(const ushort4*)(whl + (size_t)t1 * N_TOT);
            ushort4 v2 = *(const ushort4*)(whl + (size_t)t2 * N_TOT);
            ushort4 v3 = *(const ushort4*)(whl + (size_t)t3 * N_TOT);
            ushort4 v4 = *(const ushort4*)(whl + (size_t)t4 * N_TOT);
            ushort4 v5 = *(const ushort4*)(whl + (size_t)t5 * N_TOT);
            ushort4 v6 = *(const ushort4*)(whl + (size_t)t6 * N_TOT);
            ushort4 v7 = *(const ushort4*)(whl + (size_t)t7 * N_TOT);
            acc.x += ((bf2f(v0.x) + bf2f(v1.x)) + (bf2f(v2.x) + bf2f(v3.x))) + ((bf2f(v4.x) + bf2f(v5.x)) + (bf2f(v6.x) + bf2f(v7.x)));
            acc.y += ((bf2f(v0.y) + bf2f(v1.y)) + (bf2f(v2.y) + bf2f(v3.y))) + ((bf2f(v4.y) + bf2f(v5.y)) + (bf2f(v6.y) + bf2f(v7.y)));
            acc.z += ((bf2f(v0.z) + bf2f(v1.z)) + (bf2f(v2.z) + bf2f(v3.z))) + ((bf2f(v4.z) + bf2f(v5.z)) + (bf2f(v6.z) + bf2f(v7.z)));
            acc.w += ((bf2f(v0.w) + bf2f(v1.w)) + (bf2f(v2.w) + bf2f(v3.w))) + ((bf2f(v4.w) + bf2f(v5.w)) + (bf2f(v6.w) + bf2f(v7.w)));
        }
        for (; j < m; ++j) {
            int t = __shfl(e, j);
            ushort4 v = *(const ushort4*)(whl + (size_t)t * N_TOT);
            acc.x += bf2f(v.x); acc.y += bf2f(v.y); acc.z += bf2f(v.z); acc.w += bf2f(v.w);
        }
        if (deg > SLOTS) {                            // exact overflow path (cold)
            int x = r * N_NODES + n;
            int nov = min(*ovfc, OVF_CAP);
            for (int i2 = 0; i2 < nov; ++i2) {
                if (ovf[2 * i2] == x) {
                    ushort4 v = *(const ushort4*)(whl + (size_t)ovf[2 * i2 + 1] * N_TOT);
                    acc.x += bf2f(v.x); acc.y += bf2f(v.y); acc.z += bf2f(v.z); acc.w += bf2f(v.w);
                }
            }
        }
        float sc = (deg > 0) ? 1.0f / (float)deg : 0.0f;
        o0 += acc.x * sc; o1 += acc.y * sc; o2 += acc.z * sc; o3 += acc.w * sc;
    }
    f32x4 o;
    o.x = fmaxf(o0, 0.0f); o.y = fmaxf(o1, 0.0f);
    o.z = fmaxf(o2, 0.0f); o.w = fmaxf(o3, 0.0f);
    __builtin_nontemporal_store(o, (f32x4*)(out + (size_t)n * D + lane * 4));
}

extern "C" void kernel_launch(void* const* d_in, const int* in_sizes, int n_in,
                              void* d_out, int out_size, void* d_ws, size_t ws_size,
                              hipStream_t stream) {
    const float* feat = (const float*)d_in[0];
    const int* src0 = (const int*)d_in[1];
    const int* dst0 = (const int*)d_in[2];
    const int* src1 = (const int*)d_in[3];
    const int* dst1 = (const int*)d_in[4];
    const int* src2 = (const int*)d_in[5];
    const int* dst2 = (const int*)d_in[6];
    const float* W0 = (const float*)d_in[7];
    const float* b0 = (const float*)d_in[8];
    const float* W1 = (const float*)d_in[9];
    const float* b1 = (const float*)d_in[10];
    const float* W2 = (const float*)d_in[11];
    const float* b2 = (const float*)d_in[12];
    float* out = (float*)d_out;

    char* ws = (char*)d_ws;
    size_t o = 0;
    auto alloc = [&](size_t bytes) {
        size_t r = o;
        o += (bytes + 255) & ~(size_t)255;
        return r;
    };
    int* cur            = (int*)(ws + alloc((size_t)SCAN_N * 4));
    int* ovfc           = (int*)(ws + alloc(4 + (size_t)OVF_CAP * 8));
    int* ovf            = ovfc + 1;
    int* eidx           = (int*)(ws + alloc((size_t)SCAN_N * SLOTS * 4));
    unsigned short* WT  = (unsigned short*)(ws + alloc((size_t)N_TOT * D * 2));
    unsigned short* fb  = (unsigned short*)(ws + alloc((size_t)N_NODES * D * 2));
    unsigned short* Wh  = (unsigned short*)(ws + alloc((size_t)N_NODES * N_TOT * 2));

    (void)hipMemsetAsync(cur, 0, (size_t)SCAN_N * 4 + 256, stream);  // cur + ovfc
    prep_kernel<<<(N_NODES * D / 4 + 255) / 256, 256, 0, stream>>>(feat, fb, W0, W1, W2, WT);
    dim3 gg(NMB, 3);
    gemm_kernel<<<gg, 512, 0, stream>>>(fb, WT, b0, b1, b2, Wh);
    dim3 fg((3 * N_EDGES + 255) / 256, NPASS);
    fill_kernel<<<fg, 256, 0, stream>>>(src0, dst0, src1, dst1, src2, dst2, cur, eidx, ovfc, ovf);
    agg_kernel<<<(N_NODES * 64 + 255) / 256, 256, 0, stream>>>(Wh, cur, eidx, ovfc, ovf, out);
}

// Round 16
// 274.520 us; speedup vs baseline: 1.3047x; 1.0177x over previous
//
#include <hip/hip_runtime.h>
#include <hip/hip_bf16.h>

#define N_NODES 50000
#define N_EDGES 500000
#define D 256
#define N_TOT 768      // 3 * D output cols of Wh
#define SCAN_N (3 * N_NODES)
#define NMB ((N_NODES + 255) / 256)          // 196 M-blocks
#define SLOTS 32                             // fixed CSR slots/node (max deg ~25 for Poisson(10))
#define OVF_CAP 2048

typedef __attribute__((ext_vector_type(8))) __bf16 bf16x8;
typedef __attribute__((ext_vector_type(4))) float f32x4;

__device__ __forceinline__ unsigned short f2bf(float f) {
    unsigned u = __builtin_bit_cast(unsigned, f);
    u += 0x7FFFu + ((u >> 16) & 1u);   // round-to-nearest-even
    return (unsigned short)(u >> 16);
}
__device__ __forceinline__ float bf2f(unsigned short h) {
    return __builtin_bit_cast(float, (unsigned)h << 16);
}
__device__ __forceinline__ void gload16(const unsigned short* g, __bf16* l) {
    __builtin_amdgcn_global_load_lds(
        (const __attribute__((address_space(1))) void*)g,
        (__attribute__((address_space(3))) void*)l, 16, 0, 0);
}

// ---------------- fused prep+fill: feat->bf16 + W->bf16 transposed + bucket-CSR fill ----------------
// fill depends on nothing prep computes -> free fusion. prep is streaming-BW-bound,
// fill is atomic/scatter-latency-bound: complementary pipes overlap in one grid.
// Single-pass fill: bucket eidx region (19.2 MB) < 32 MB aggregate L2, scatter merges.
__global__ void prep_kernel(const float* __restrict__ feat, unsigned short* __restrict__ fb,
                            const float* __restrict__ W0, const float* __restrict__ W1,
                            const float* __restrict__ W2, unsigned short* __restrict__ WT,
                            const int* __restrict__ s0, const int* __restrict__ d0,
                            const int* __restrict__ s1, const int* __restrict__ d1,
                            const int* __restrict__ s2, const int* __restrict__ d2,
                            int* __restrict__ cur, int* __restrict__ eidx,
                            int* __restrict__ ovfc, int* __restrict__ ovf) {
    int i = blockIdx.x * blockDim.x + threadIdx.x;
    if (i < N_NODES * D / 4) {                       // 3.2M float4 slots
        float4 v = ((const float4*)feat)[i];
        ushort4 pk;
        pk.x = f2bf(v.x); pk.y = f2bf(v.y); pk.z = f2bf(v.z); pk.w = f2bf(v.w);
        ((ushort4*)fb)[i] = pk;
    }
    if (i < N_TOT * D) {                             // 196608: WT[j][k] = W_r[k][c]
        int j = i >> 8, k = i & 255;
        int r = j >> 8, c = j & 255;
        const float* W = (r == 0) ? W0 : (r == 1) ? W1 : W2;
        WT[i] = f2bf(W[k * D + c]);
    }
    if (i < 3 * N_EDGES) {                           // bucket-CSR fill (cur pre-zeroed)
        int r = i / N_EDGES;
        int e = i - r * N_EDGES;
        const int* d = (r == 0) ? d0 : (r == 1) ? d1 : d2;
        const int* s = (r == 0) ? s0 : (r == 1) ? s1 : s2;
        int x = r * N_NODES + d[e];
        int rank = atomicAdd(&cur[x], 1);
        if (rank < SLOTS) {
            eidx[(size_t)x * SLOTS + rank] = s[e];
        } else {                                     // provably-cold exact overflow
            int op = atomicAdd(ovfc, 1);
            if (op < OVF_CAP) { ovf[2 * op] = x; ovf[2 * op + 1] = s[e]; }
        }
    }
}

// ---------------- GEMM-FIRST: Wh[n][r*256+c] = bf16( feat[n] @ W_r + b_r ) ----------------
// K = 256 -> only 4 K-steps of BK=64 (per-step drain ~4.7us is the empirical law).
// 2-buffer LDS (128 KB), fully unrolled, stage-ahead; swizzle slot^(row&7) both sides
// (linear LDS dest for global_load_lds + pre-swizzled global src + swizzled ds_read).
__global__ __launch_bounds__(512) void gemm_kernel(
    const unsigned short* __restrict__ A, const unsigned short* __restrict__ BT,
    const float* __restrict__ b0, const float* __restrict__ b1, const float* __restrict__ b2,
    unsigned short* __restrict__ Wh) {
    __shared__ __bf16 Asl[2][256][64];   // 2 x 32 KB
    __shared__ __bf16 Bsl[2][256][64];   // 2 x 32 KB
    int tid = threadIdx.x;
    int lane = tid & 63, w = tid >> 6;   // 8 waves
    int wr = w >> 2, wc = w & 3;         // wave tile: 128 rows x 64 cols
    int m0 = blockIdx.x * 256;
    int p = blockIdx.y;                  // relation panel 0..2
    const float* bp = (p == 0) ? b0 : (p == 1) ? b1 : b2;
    f32x4 acc[8][4] = {};

    auto stage = [&](int kt, int b) {
        #pragma unroll
        for (int i = 0; i < 4; ++i) {
            int slot = i * 512 + w * 64 + lane;        // 16B slots, wave-contiguous LDS
            int row = slot >> 3, ks = slot & 7;
            int g = ks ^ (row & 7);                    // pre-swizzled global k-slot
            int gm = m0 + row; if (gm >= N_NODES) gm = N_NODES - 1;
            gload16(A + (size_t)gm * D + kt * 64 + g * 8,
                    &Asl[b][0][0] + (size_t)slot * 8);
            gload16(BT + (size_t)(p * 256 + row) * D + kt * 64 + g * 8,
                    &Bsl[b][0][0] + (size_t)slot * 8);
        }
    };

    stage(0, 0);
    int rr = lane & 15, q = lane >> 4;
    #pragma unroll
    for (int kt = 0; kt < 4; ++kt) {
        asm volatile("s_waitcnt vmcnt(0)" ::: "memory");   // buf kt loads landed
        __builtin_amdgcn_s_barrier();
        int b = kt & 1;
        if (kt + 1 < 4) stage(kt + 1, b ^ 1);              // hide under compute below
        #pragma unroll
        for (int kh = 0; kh < 2; ++kh) {                   // two k-halves of BK=64
            bf16x8 af[8], bfr[4];
            #pragma unroll
            for (int mf = 0; mf < 8; ++mf) {
                int row = wr * 128 + mf * 16 + rr;
                int sl = (kh * 4 + q) ^ (row & 7);
                af[mf] = *(const bf16x8*)(&Asl[b][row][0] + sl * 8);
            }
            #pragma unroll
            for (int nf = 0; nf < 4; ++nf) {
                int row = wc * 64 + nf * 16 + rr;
                int sl = (kh * 4 + q) ^ (row & 7);
                bfr[nf] = *(const bf16x8*)(&Bsl[b][row][0] + sl * 8);
            }
            #pragma unroll
            for (int mf = 0; mf < 8; ++mf)
                #pragma unroll
                for (int nf = 0; nf < 4; ++nf)
                    acc[mf][nf] = __builtin_amdgcn_mfma_f32_16x16x32_bf16(af[mf], bfr[nf], acc[mf][nf], 0, 0, 0);
        }
        __builtin_amdgcn_s_barrier();                      // done reading buf b
    }

    // epilogue: +bias, cast bf16; C/D layout: col = lane&15, row = (lane>>4)*4 + reg
    #pragma unroll
    for (int mf = 0; mf < 8; ++mf) {
        #pragma unroll
        for (int nf = 0; nf < 4; ++nf) {
            int col = wc * 64 + nf * 16 + rr;
            float bb = bp[col];
            #pragma unroll
            for (int reg = 0; reg < 4; ++reg) {
                int row = m0 + wr * 128 + mf * 16 + q * 4 + reg;
                if (row < N_NODES)
                    Wh[(size_t)row * N_TOT + p * 256 + col] = f2bf(acc[mf][nf][reg] + bb);
            }
        }
    }
}

// ---------------- final: per-node gather Wh, mean per relation, sum, relu -> out (f32) ----------------
// One wave per node, all 3 relations; lane owns 4 channels (8B loads); 8-deep
// independent gathers. Bias already inside Wh -> deg=0 relations contribute exactly 0.
__global__ void agg_kernel(const unsigned short* __restrict__ Wh, const int* __restrict__ cur,
                           const int* __restrict__ eidx, const int* __restrict__ ovfc,
                           const int* __restrict__ ovf, float* __restrict__ out) {
    int n = (blockIdx.x * blockDim.x + threadIdx.x) >> 6;
    int lane = threadIdx.x & 63;
    if (n >= N_NODES) return;

    int dg3[3], e3[3];
    #pragma unroll
    for (int r = 0; r < 3; ++r)
        dg3[r] = cur[r * N_NODES + n];
    #pragma unroll
    for (int r = 0; r < 3; ++r) {                     // 3 head-loads in flight together
        int x = r * N_NODES + n;
        e3[r] = (lane < min(dg3[r], SLOTS)) ? eidx[(size_t)x * SLOTS + lane] : 0;
    }

    float o0 = 0.f, o1 = 0.f, o2 = 0.f, o3 = 0.f;
    #pragma unroll
    for (int r = 0; r < 3; ++r) {
        const unsigned short* whl = Wh + r * 256 + lane * 4;
        int deg = dg3[r];
        int m = min(deg, SLOTS);
        int e = e3[r];
        float4 acc = make_float4(0.f, 0.f, 0.f, 0.f);
        int j = 0;
        for (; j + 7 < m; j += 8) {
            int t0 = __shfl(e, j + 0), t1 = __shfl(e, j + 1), t2 = __shfl(e, j + 2), t3 = __shfl(e, j + 3);
            int t4 = __shfl(e, j + 4), t5 = __shfl(e, j + 5), t6 = __shfl(e, j + 6), t7 = __shfl(e, j + 7);
            ushort4 v0 = *(const ushort4*)(whl + (size_t)t0 * N_TOT);
            ushort4 v1 = *(const ushort4*)(whl + (size_t)t1 * N_TOT);
            ushort4 v2 = *(const ushort4*)(whl + (size_t)t2 * N_TOT);
            ushort4 v3 = *(const ushort4*)(whl + (size_t)t3 * N_TOT);
            ushort4 v4 = *(const ushort4*)(whl + (size_t)t4 * N_TOT);
            ushort4 v5 = *(const ushort4*)(whl + (size_t)t5 * N_TOT);
            ushort4 v6 = *(const ushort4*)(whl + (size_t)t6 * N_TOT);
            ushort4 v7 = *(const ushort4*)(whl + (size_t)t7 * N_TOT);
            acc.x += ((bf2f(v0.x) + bf2f(v1.x)) + (bf2f(v2.x) + bf2f(v3.x))) + ((bf2f(v4.x) + bf2f(v5.x)) + (bf2f(v6.x) + bf2f(v7.x)));
            acc.y += ((bf2f(v0.y) + bf2f(v1.y)) + (bf2f(v2.y) + bf2f(v3.y))) + ((bf2f(v4.y) + bf2f(v5.y)) + (bf2f(v6.y) + bf2f(v7.y)));
            acc.z += ((bf2f(v0.z) + bf2f(v1.z)) + (bf2f(v2.z) + bf2f(v3.z))) + ((bf2f(v4.z) + bf2f(v5.z)) + (bf2f(v6.z) + bf2f(v7.z)));
            acc.w += ((bf2f(v0.w) + bf2f(v1.w)) + (bf2f(v2.w) + bf2f(v3.w))) + ((bf2f(v4.w) + bf2f(v5.w)) + (bf2f(v6.w) + bf2f(v7.w)));
        }
        for (; j < m; ++j) {
            int t = __shfl(e, j);
            ushort4 v = *(const ushort4*)(whl + (size_t)t * N_TOT);
            acc.x += bf2f(v.x); acc.y += bf2f(v.y); acc.z += bf2f(v.z); acc.w += bf2f(v.w);
        }
        if (deg > SLOTS) {                            // exact overflow path (cold)
            int x = r * N_NODES + n;
            int nov = min(*ovfc, OVF_CAP);
            for (int i2 = 0; i2 < nov; ++i2) {
                if (ovf[2 * i2] == x) {
                    ushort4 v = *(const ushort4*)(whl + (size_t)ovf[2 * i2 + 1] * N_TOT);
                    acc.x += bf2f(v.x); acc.y += bf2f(v.y); acc.z += bf2f(v.z); acc.w += bf2f(v.w);
                }
            }
        }
        float sc = (deg > 0) ? 1.0f / (float)deg : 0.0f;
        o0 += acc.x * sc; o1 += acc.y * sc; o2 += acc.z * sc; o3 += acc.w * sc;
    }
    f32x4 o;
    o.x = fmaxf(o0, 0.0f); o.y = fmaxf(o1, 0.0f);
    o.z = fmaxf(o2, 0.0f); o.w = fmaxf(o3, 0.0f);
    __builtin_nontemporal_store(o, (f32x4*)(out + (size_t)n * D + lane * 4));
}

extern "C" void kernel_launch(void* const* d_in, const int* in_sizes, int n_in,
                              void* d_out, int out_size, void* d_ws, size_t ws_size,
                              hipStream_t stream) {
    const float* feat = (const float*)d_in[0];
    const int* src0 = (const int*)d_in[1];
    const int* dst0 = (const int*)d_in[2];
    const int* src1 = (const int*)d_in[3];
    const int* dst1 = (const int*)d_in[4];
    const int* src2 = (const int*)d_in[5];
    const int* dst2 = (const int*)d_in[6];
    const float* W0 = (const float*)d_in[7];
    const float* b0 = (const float*)d_in[8];
    const float* W1 = (const float*)d_in[9];
    const float* b1 = (const float*)d_in[10];
    const float* W2 = (const float*)d_in[11];
    const float* b2 = (const float*)d_in[12];
    float* out = (float*)d_out;

    char* ws = (char*)d_ws;
    size_t o = 0;
    auto alloc = [&](size_t bytes) {
        size_t r = o;
        o += (bytes + 255) & ~(size_t)255;
        return r;
    };
    int* cur            = (int*)(ws + alloc((size_t)SCAN_N * 4));
    int* ovfc           = (int*)(ws + alloc(4 + (size_t)OVF_CAP * 8));
    int* ovf            = ovfc + 1;
    int* eidx           = (int*)(ws + alloc((size_t)SCAN_N * SLOTS * 4));
    unsigned short* WT  = (unsigned short*)(ws + alloc((size_t)N_TOT * D * 2));
    unsigned short* fb  = (unsigned short*)(ws + alloc((size_t)N_NODES * D * 2));
    unsigned short* Wh  = (unsigned short*)(ws + alloc((size_t)N_NODES * N_TOT * 2));

    (void)hipMemsetAsync(cur, 0, (size_t)SCAN_N * 4 + 256, stream);  // cur + ovfc
    prep_kernel<<<(N_NODES * D / 4 + 255) / 256, 256, 0, stream>>>(
        feat, fb, W0, W1, W2, WT,
        src0, dst0, src1, dst1, src2, dst2, cur, eidx, ovfc, ovf);
    dim3 gg(NMB, 3);
    gemm_kernel<<<gg, 512, 0, stream>>>(fb, WT, b0, b1, b2, Wh);
    agg_kernel<<<(N_NODES * 64 + 255) / 256, 256, 0, stream>>>(Wh, cur, eidx, ovfc, ovf, out);
}

// Round 17
// 271.182 us; speedup vs baseline: 1.3207x; 1.0123x over previous
//
#include <hip/hip_runtime.h>
#include <hip/hip_bf16.h>

#define N_NODES 50000
#define N_EDGES 500000
#define D 256
#define N_TOT 768      // 3 * D output cols of Wh
#define SCAN_N (3 * N_NODES)
#define NMB ((N_NODES + 255) / 256)          // 196 M-blocks
#define SLOTS 32                             // 32 x u16 = 64 B = ONE cache line per (r,node)
#define OVF_CAP 2048

typedef __attribute__((ext_vector_type(8))) __bf16 bf16x8;
typedef __attribute__((ext_vector_type(4))) float f32x4;

__device__ __forceinline__ unsigned short f2bf(float f) {
    unsigned u = __builtin_bit_cast(unsigned, f);
    u += 0x7FFFu + ((u >> 16) & 1u);   // round-to-nearest-even
    return (unsigned short)(u >> 16);
}
__device__ __forceinline__ float bf2f(unsigned short h) {
    return __builtin_bit_cast(float, (unsigned)h << 16);
}
__device__ __forceinline__ void gload16(const unsigned short* g, __bf16* l) {
    __builtin_amdgcn_global_load_lds(
        (const __attribute__((address_space(1))) void*)g,
        (__attribute__((address_space(3))) void*)l, 16, 0, 0);
}

// ---------------- fused prep+fill: feat->bf16 + W->bf16 transposed + bucket-CSR fill ----------------
// eidx is uint16 (src < 50000 < 65536): a node's whole bucket = one 64B line, so the
// random scatter's dirty-line traffic halves+ vs int32 (partial-line HBM RMW was the cost).
__global__ void prep_kernel(const float* __restrict__ feat, unsigned short* __restrict__ fb,
                            const float* __restrict__ W0, const float* __restrict__ W1,
                            const float* __restrict__ W2, unsigned short* __restrict__ WT,
                            const int* __restrict__ s0, const int* __restrict__ d0,
                            const int* __restrict__ s1, const int* __restrict__ d1,
                            const int* __restrict__ s2, const int* __restrict__ d2,
                            int* __restrict__ cur, unsigned short* __restrict__ eidx,
                            int* __restrict__ ovfc, int* __restrict__ ovf) {
    int i = blockIdx.x * blockDim.x + threadIdx.x;
    if (i < N_NODES * D / 4) {                       // 3.2M float4 slots
        float4 v = ((const float4*)feat)[i];
        ushort4 pk;
        pk.x = f2bf(v.x); pk.y = f2bf(v.y); pk.z = f2bf(v.z); pk.w = f2bf(v.w);
        ((ushort4*)fb)[i] = pk;
    }
    if (i < N_TOT * D) {                             // 196608: WT[j][k] = W_r[k][c]
        int j = i >> 8, k = i & 255;
        int r = j >> 8, c = j & 255;
        const float* W = (r == 0) ? W0 : (r == 1) ? W1 : W2;
        WT[i] = f2bf(W[k * D + c]);
    }
    if (i < 3 * N_EDGES) {                           // bucket-CSR fill (cur pre-zeroed)
        int r = i / N_EDGES;
        int e = i - r * N_EDGES;
        const int* d = (r == 0) ? d0 : (r == 1) ? d1 : d2;
        const int* s = (r == 0) ? s0 : (r == 1) ? s1 : s2;
        int x = r * N_NODES + d[e];
        int rank = atomicAdd(&cur[x], 1);
        if (rank < SLOTS) {
            eidx[(size_t)x * SLOTS + rank] = (unsigned short)s[e];
        } else {                                     // provably-cold exact overflow
            int op = atomicAdd(ovfc, 1);
            if (op < OVF_CAP) { ovf[2 * op] = x; ovf[2 * op + 1] = s[e]; }
        }
    }
}

// ---------------- GEMM-FIRST: Wh[n][r*256+c] = bf16( feat[n] @ W_r + b_r ) ----------------
// K = 256 -> only 4 K-steps of BK=64 (per-step drain ~4.7us is the empirical law).
// 2-buffer LDS (128 KB), fully unrolled, stage-ahead; swizzle slot^(row&7) both sides
// (linear LDS dest for global_load_lds + pre-swizzled global src + swizzled ds_read).
__global__ __launch_bounds__(512) void gemm_kernel(
    const unsigned short* __restrict__ A, const unsigned short* __restrict__ BT,
    const float* __restrict__ b0, const float* __restrict__ b1, const float* __restrict__ b2,
    unsigned short* __restrict__ Wh) {
    __shared__ __bf16 Asl[2][256][64];   // 2 x 32 KB
    __shared__ __bf16 Bsl[2][256][64];   // 2 x 32 KB
    int tid = threadIdx.x;
    int lane = tid & 63, w = tid >> 6;   // 8 waves
    int wr = w >> 2, wc = w & 3;         // wave tile: 128 rows x 64 cols
    int m0 = blockIdx.x * 256;
    int p = blockIdx.y;                  // relation panel 0..2
    const float* bp = (p == 0) ? b0 : (p == 1) ? b1 : b2;
    f32x4 acc[8][4] = {};

    auto stage = [&](int kt, int b) {
        #pragma unroll
        for (int i = 0; i < 4; ++i) {
            int slot = i * 512 + w * 64 + lane;        // 16B slots, wave-contiguous LDS
            int row = slot >> 3, ks = slot & 7;
            int g = ks ^ (row & 7);                    // pre-swizzled global k-slot
            int gm = m0 + row; if (gm >= N_NODES) gm = N_NODES - 1;
            gload16(A + (size_t)gm * D + kt * 64 + g * 8,
                    &Asl[b][0][0] + (size_t)slot * 8);
            gload16(BT + (size_t)(p * 256 + row) * D + kt * 64 + g * 8,
                    &Bsl[b][0][0] + (size_t)slot * 8);
        }
    };

    stage(0, 0);
    int rr = lane & 15, q = lane >> 4;
    #pragma unroll
    for (int kt = 0; kt < 4; ++kt) {
        asm volatile("s_waitcnt vmcnt(0)" ::: "memory");   // buf kt loads landed
        __builtin_amdgcn_s_barrier();
        int b = kt & 1;
        if (kt + 1 < 4) stage(kt + 1, b ^ 1);              // hide under compute below
        #pragma unroll
        for (int kh = 0; kh < 2; ++kh) {                   // two k-halves of BK=64
            bf16x8 af[8], bfr[4];
            #pragma unroll
            for (int mf = 0; mf < 8; ++mf) {
                int row = wr * 128 + mf * 16 + rr;
                int sl = (kh * 4 + q) ^ (row & 7);
                af[mf] = *(const bf16x8*)(&Asl[b][row][0] + sl * 8);
            }
            #pragma unroll
            for (int nf = 0; nf < 4; ++nf) {
                int row = wc * 64 + nf * 16 + rr;
                int sl = (kh * 4 + q) ^ (row & 7);
                bfr[nf] = *(const bf16x8*)(&Bsl[b][row][0] + sl * 8);
            }
            #pragma unroll
            for (int mf = 0; mf < 8; ++mf)
                #pragma unroll
                for (int nf = 0; nf < 4; ++nf)
                    acc[mf][nf] = __builtin_amdgcn_mfma_f32_16x16x32_bf16(af[mf], bfr[nf], acc[mf][nf], 0, 0, 0);
        }
        __builtin_amdgcn_s_barrier();                      // done reading buf b
    }

    // epilogue: +bias, cast bf16; C/D layout: col = lane&15, row = (lane>>4)*4 + reg
    #pragma unroll
    for (int mf = 0; mf < 8; ++mf) {
        #pragma unroll
        for (int nf = 0; nf < 4; ++nf) {
            int col = wc * 64 + nf * 16 + rr;
            float bb = bp[col];
            #pragma unroll
            for (int reg = 0; reg < 4; ++reg) {
                int row = m0 + wr * 128 + mf * 16 + q * 4 + reg;
                if (row < N_NODES)
                    Wh[(size_t)row * N_TOT + p * 256 + col] = f2bf(acc[mf][nf][reg] + bb);
            }
        }
    }
}

// ---------------- final: per-node gather Wh, mean per relation, sum, relu -> out (f32) ----------------
// One wave per node, all 3 relations; lane owns 4 channels (8B loads); 8-deep
// independent gathers. Bias already inside Wh -> deg=0 relations contribute exactly 0.
__global__ void agg_kernel(const unsigned short* __restrict__ Wh, const int* __restrict__ cur,
                           const unsigned short* __restrict__ eidx, const int* __restrict__ ovfc,
                           const int* __restrict__ ovf, float* __restrict__ out) {
    int n = (blockIdx.x * blockDim.x + threadIdx.x) >> 6;
    int lane = threadIdx.x & 63;
    if (n >= N_NODES) return;

    int dg3[3], e3[3];
    #pragma unroll
    for (int r = 0; r < 3; ++r)
        dg3[r] = cur[r * N_NODES + n];
    #pragma unroll
    for (int r = 0; r < 3; ++r) {                     // 3 head-loads in flight together
        int x = r * N_NODES + n;
        e3[r] = (lane < min(dg3[r], SLOTS)) ? (int)eidx[(size_t)x * SLOTS + lane] : 0;
    }

    float o0 = 0.f, o1 = 0.f, o2 = 0.f, o3 = 0.f;
    #pragma unroll
    for (int r = 0; r < 3; ++r) {
        const unsigned short* whl = Wh + r * 256 + lane * 4;
        int deg = dg3[r];
        int m = min(deg, SLOTS);
        int e = e3[r];
        float4 acc = make_float4(0.f, 0.f, 0.f, 0.f);
        int j = 0;
        for (; j + 7 < m; j += 8) {
            int t0 = __shfl(e, j + 0), t1 = __shfl(e, j + 1), t2 = __shfl(e, j + 2), t3 = __shfl(e, j + 3);
            int t4 = __shfl(e, j + 4), t5 = __shfl(e, j + 5), t6 = __shfl(e, j + 6), t7 = __shfl(e, j + 7);
            ushort4 v0 = *(const ushort4*)(whl + (size_t)t0 * N_TOT);
            ushort4 v1 = *(const ushort4*)(whl + (size_t)t1 * N_TOT);
            ushort4 v2 = *(const ushort4*)(whl + (size_t)t2 * N_TOT);
            ushort4 v3 = *(const ushort4*)(whl + (size_t)t3 * N_TOT);
            ushort4 v4 = *(const ushort4*)(whl + (size_t)t4 * N_TOT);
            ushort4 v5 = *(const ushort4*)(whl + (size_t)t5 * N_TOT);
            ushort4 v6 = *(const ushort4*)(whl + (size_t)t6 * N_TOT);
            ushort4 v7 = *(const ushort4*)(whl + (size_t)t7 * N_TOT);
            acc.x += ((bf2f(v0.x) + bf2f(v1.x)) + (bf2f(v2.x) + bf2f(v3.x))) + ((bf2f(v4.x) + bf2f(v5.x)) + (bf2f(v6.x) + bf2f(v7.x)));
            acc.y += ((bf2f(v0.y) + bf2f(v1.y)) + (bf2f(v2.y) + bf2f(v3.y))) + ((bf2f(v4.y) + bf2f(v5.y)) + (bf2f(v6.y) + bf2f(v7.y)));
            acc.z += ((bf2f(v0.z) + bf2f(v1.z)) + (bf2f(v2.z) + bf2f(v3.z))) + ((bf2f(v4.z) + bf2f(v5.z)) + (bf2f(v6.z) + bf2f(v7.z)));
            acc.w += ((bf2f(v0.w) + bf2f(v1.w)) + (bf2f(v2.w) + bf2f(v3.w))) + ((bf2f(v4.w) + bf2f(v5.w)) + (bf2f(v6.w) + bf2f(v7.w)));
        }
        for (; j < m; ++j) {
            int t = __shfl(e, j);
            ushort4 v = *(const ushort4*)(whl + (size_t)t * N_TOT);
            acc.x += bf2f(v.x); acc.y += bf2f(v.y); acc.z += bf2f(v.z); acc.w += bf2f(v.w);
        }
        if (deg > SLOTS) {                            // exact overflow path (cold)
            int x = r * N_NODES + n;
            int nov = min(*ovfc, OVF_CAP);
            for (int i2 = 0; i2 < nov; ++i2) {
                if (ovf[2 * i2] == x) {
                    ushort4 v = *(const ushort4*)(whl + (size_t)ovf[2 * i2 + 1] * N_TOT);
                    acc.x += bf2f(v.x); acc.y += bf2f(v.y); acc.z += bf2f(v.z); acc.w += bf2f(v.w);
                }
            }
        }
        float sc = (deg > 0) ? 1.0f / (float)deg : 0.0f;
        o0 += acc.x * sc; o1 += acc.y * sc; o2 += acc.z * sc; o3 += acc.w * sc;
    }
    f32x4 o;
    o.x = fmaxf(o0, 0.0f); o.y = fmaxf(o1, 0.0f);
    o.z = fmaxf(o2, 0.0f); o.w = fmaxf(o3, 0.0f);
    __builtin_nontemporal_store(o, (f32x4*)(out + (size_t)n * D + lane * 4));
}

extern "C" void kernel_launch(void* const* d_in, const int* in_sizes, int n_in,
                              void* d_out, int out_size, void* d_ws, size_t ws_size,
                              hipStream_t stream) {
    const float* feat = (const float*)d_in[0];
    const int* src0 = (const int*)d_in[1];
    const int* dst0 = (const int*)d_in[2];
    const int* src1 = (const int*)d_in[3];
    const int* dst1 = (const int*)d_in[4];
    const int* src2 = (const int*)d_in[5];
    const int* dst2 = (const int*)d_in[6];
    const float* W0 = (const float*)d_in[7];
    const float* b0 = (const float*)d_in[8];
    const float* W1 = (const float*)d_in[9];
    const float* b1 = (const float*)d_in[10];
    const float* W2 = (const float*)d_in[11];
    const float* b2 = (const float*)d_in[12];
    float* out = (float*)d_out;

    char* ws = (char*)d_ws;
    size_t o = 0;
    auto alloc = [&](size_t bytes) {
        size_t r = o;
        o += (bytes + 255) & ~(size_t)255;
        return r;
    };
    int* cur            = (int*)(ws + alloc((size_t)SCAN_N * 4));
    int* ovfc           = (int*)(ws + alloc(4 + (size_t)OVF_CAP * 8));
    int* ovf            = ovfc + 1;
    unsigned short* eidx = (unsigned short*)(ws + alloc((size_t)SCAN_N * SLOTS * 2));
    unsigned short* WT  = (unsigned short*)(ws + alloc((size_t)N_TOT * D * 2));
    unsigned short* fb  = (unsigned short*)(ws + alloc((size_t)N_NODES * D * 2));
    unsigned short* Wh  = (unsigned short*)(ws + alloc((size_t)N_NODES * N_TOT * 2));

    (void)hipMemsetAsync(cur, 0, (size_t)SCAN_N * 4 + 256, stream);  // cur + ovfc
    prep_kernel<<<(N_NODES * D / 4 + 255) / 256, 256, 0, stream>>>(
        feat, fb, W0, W1, W2, WT,
        src0, dst0, src1, dst1, src2, dst2, cur, eidx, ovfc, ovf);
    dim3 gg(NMB, 3);
    gemm_kernel<<<gg, 512, 0, stream>>>(fb, WT, b0, b1, b2, Wh);
    agg_kernel<<<(N_NODES * 64 + 255) / 256, 256, 0, stream>>>(Wh, cur, eidx, ovfc, ovf, out);
}

// Round 18
// 248.377 us; speedup vs baseline: 1.4420x; 1.0918x over previous
//
#include <hip/hip_runtime.h>
#include <hip/hip_bf16.h>

#define N_NODES 50000
#define N_EDGES 500000
#define D 256
#define N_TOT 768      // 3 * D output cols of Wh
#define SCAN_N (3 * N_NODES)
#define NMB ((N_NODES + 255) / 256)          // 196 M-blocks
#define NBLK (NMB * 3)                       // 588 gemm blocks
#define JOBS (3 * N_EDGES)                   // 1.5M fill jobs
#define JPB ((JOBS + NBLK - 1) / NBLK)       // 2552 jobs per block
#define CPB ((JPB + 7) / 8)                  // 319 jobs per chunk
#define SLOTS 32                             // 32 x u16 = 64 B = ONE cache line per (r,node)
#define OVF_CAP 2048

typedef __attribute__((ext_vector_type(8))) __bf16 bf16x8;
typedef __attribute__((ext_vector_type(4))) float f32x4;

__device__ __forceinline__ unsigned short f2bf(float f) {
    unsigned u = __builtin_bit_cast(unsigned, f);
    u += 0x7FFFu + ((u >> 16) & 1u);   // round-to-nearest-even
    return (unsigned short)(u >> 16);
}
__device__ __forceinline__ float bf2f(unsigned short h) {
    return __builtin_bit_cast(float, (unsigned)h << 16);
}
__device__ __forceinline__ void gload16(const unsigned short* g, __bf16* l) {
    __builtin_amdgcn_global_load_lds(
        (const __attribute__((address_space(1))) void*)g,
        (__attribute__((address_space(3))) void*)l, 16, 0, 0);
}

// ---------------- prep: feat->bf16 + W->bf16 transposed (pure streaming now) ----------------
// WT layout: [768 outcols j=r*256+c][256 k], WT[j][k] = W_r[k][c]
__global__ void prep_kernel(const float* __restrict__ feat, unsigned short* __restrict__ fb,
                            const float* __restrict__ W0, const float* __restrict__ W1,
                            const float* __restrict__ W2, unsigned short* __restrict__ WT) {
    int i = blockIdx.x * blockDim.x + threadIdx.x;
    if (i < N_NODES * D / 4) {                       // 3.2M float4 slots
        float4 v = ((const float4*)feat)[i];
        ushort4 pk;
        pk.x = f2bf(v.x); pk.y = f2bf(v.y); pk.z = f2bf(v.z); pk.w = f2bf(v.w);
        ((ushort4*)fb)[i] = pk;
    }
    if (i < N_TOT * D) {                             // 196608: WT[j][k] = W_r[k][c]
        int j = i >> 8, k = i & 255;
        int r = j >> 8, c = j & 255;
        const float* W = (r == 0) ? W0 : (r == 1) ? W1 : W2;
        WT[i] = f2bf(W[k * D + c]);
    }
}

// ---------------- fused GEMM + FILL: two wave roles in one 768-thread block ----------------
// Waves 0-7 (tid<512): Wh[n][p*256+c] = bf16(feat[n] @ W_p + b_p) -- unchanged gemm,
//   exactly 8 s_barriers (2 per kt x 4).
// Waves 8-11 (tid>=512): bucket-CSR fill of this block's JPB-job slice in 8 chunks,
//   one s_barrier per chunk (counts match; wave-uniform branch; no early exit).
// Mechanism: the fill path's atomic/scatter latency uses no MFMA/LDS/VALU resources,
// so it hides under gemm's compute intervals (and gemm's drain hides under fill).
__global__ __launch_bounds__(768) void gemm_kernel(
    const unsigned short* __restrict__ A, const unsigned short* __restrict__ BT,
    const float* __restrict__ b0, const float* __restrict__ b1, const float* __restrict__ b2,
    unsigned short* __restrict__ Wh,
    const int* __restrict__ s0, const int* __restrict__ d0,
    const int* __restrict__ s1, const int* __restrict__ d1,
    const int* __restrict__ s2, const int* __restrict__ d2,
    int* __restrict__ cur, unsigned short* __restrict__ eidx,
    int* __restrict__ ovfc, int* __restrict__ ovf) {
    __shared__ __bf16 Asl[2][256][64];   // 2 x 32 KB
    __shared__ __bf16 Bsl[2][256][64];   // 2 x 32 KB
    int tid = threadIdx.x;
    int bid = blockIdx.y * NMB + blockIdx.x;         // 0..587

    if (tid < 512) {
        // ---------------- gemm role (unchanged structure) ----------------
        int lane = tid & 63, w = tid >> 6;   // 8 waves
        int wr = w >> 2, wc = w & 3;         // wave tile: 128 rows x 64 cols
        int m0 = blockIdx.x * 256;
        int p = blockIdx.y;                  // relation panel 0..2
        const float* bp = (p == 0) ? b0 : (p == 1) ? b1 : b2;
        f32x4 acc[8][4] = {};

        auto stage = [&](int kt, int b) {
            #pragma unroll
            for (int i = 0; i < 4; ++i) {
                int slot = i * 512 + w * 64 + lane;        // 16B slots, wave-contiguous LDS
                int row = slot >> 3, ks = slot & 7;
                int g = ks ^ (row & 7);                    // pre-swizzled global k-slot
                int gm = m0 + row; if (gm >= N_NODES) gm = N_NODES - 1;
                gload16(A + (size_t)gm * D + kt * 64 + g * 8,
                        &Asl[b][0][0] + (size_t)slot * 8);
                gload16(BT + (size_t)(p * 256 + row) * D + kt * 64 + g * 8,
                        &Bsl[b][0][0] + (size_t)slot * 8);
            }
        };

        stage(0, 0);
        int rr = lane & 15, q = lane >> 4;
        #pragma unroll
        for (int kt = 0; kt < 4; ++kt) {
            asm volatile("s_waitcnt vmcnt(0)" ::: "memory");   // buf kt loads landed
            __builtin_amdgcn_s_barrier();                      // barrier A (x4)
            int b = kt & 1;
            if (kt + 1 < 4) stage(kt + 1, b ^ 1);              // hide under compute below
            #pragma unroll
            for (int kh = 0; kh < 2; ++kh) {                   // two k-halves of BK=64
                bf16x8 af[8], bfr[4];
                #pragma unroll
                for (int mf = 0; mf < 8; ++mf) {
                    int row = wr * 128 + mf * 16 + rr;
                    int sl = (kh * 4 + q) ^ (row & 7);
                    af[mf] = *(const bf16x8*)(&Asl[b][row][0] + sl * 8);
                }
                #pragma unroll
                for (int nf = 0; nf < 4; ++nf) {
                    int row = wc * 64 + nf * 16 + rr;
                    int sl = (kh * 4 + q) ^ (row & 7);
                    bfr[nf] = *(const bf16x8*)(&Bsl[b][row][0] + sl * 8);
                }
                #pragma unroll
                for (int mf = 0; mf < 8; ++mf)
                    #pragma unroll
                    for (int nf = 0; nf < 4; ++nf)
                        acc[mf][nf] = __builtin_amdgcn_mfma_f32_16x16x32_bf16(af[mf], bfr[nf], acc[mf][nf], 0, 0, 0);
            }
            __builtin_amdgcn_s_barrier();                      // barrier B (x4)
        }

        // epilogue: +bias, cast bf16; C/D layout: col = lane&15, row = (lane>>4)*4 + reg
        #pragma unroll
        for (int mf = 0; mf < 8; ++mf) {
            #pragma unroll
            for (int nf = 0; nf < 4; ++nf) {
                int col = wc * 64 + nf * 16 + rr;
                float bb = bp[col];
                #pragma unroll
                for (int reg = 0; reg < 4; ++reg) {
                    int row = m0 + wr * 128 + mf * 16 + q * 4 + reg;
                    if (row < N_NODES)
                        Wh[(size_t)row * N_TOT + p * 256 + col] = f2bf(acc[mf][nf][reg] + bb);
                }
            }
        }
    } else {
        // ---------------- fill role: 8 chunks, 1 barrier each (matches gemm's 8) ----------------
        int ft = tid - 512;                          // 0..255
        int jb0 = bid * JPB;
        int jend = jb0 + JPB; if (jend > JOBS) jend = JOBS;
        #pragma unroll 1
        for (int c = 0; c < 8; ++c) {
            int cs = jb0 + c * CPB;
            int ce = cs + CPB; if (ce > jend) ce = jend;
            for (int j = cs + ft; j < ce; j += 256) {
                int r = j / N_EDGES;
                int e = j - r * N_EDGES;
                const int* d = (r == 0) ? d0 : (r == 1) ? d1 : d2;
                const int* s = (r == 0) ? s0 : (r == 1) ? s1 : s2;
                int x = r * N_NODES + d[e];
                int rank = atomicAdd(&cur[x], 1);
                if (rank < SLOTS) {
                    eidx[(size_t)x * SLOTS + rank] = (unsigned short)s[e];
                } else {                             // provably-cold exact overflow
                    int op = atomicAdd(ovfc, 1);
                    if (op < OVF_CAP) { ovf[2 * op] = x; ovf[2 * op + 1] = s[e]; }
                }
            }
            __builtin_amdgcn_s_barrier();
        }
    }
}

// ---------------- final: per-node gather Wh, mean per relation, sum, relu -> out (f32) ----------------
// One wave per node, all 3 relations; lane owns 4 channels (8B loads); 8-deep
// independent gathers. Bias already inside Wh -> deg=0 relations contribute exactly 0.
__global__ void agg_kernel(const unsigned short* __restrict__ Wh, const int* __restrict__ cur,
                           const unsigned short* __restrict__ eidx, const int* __restrict__ ovfc,
                           const int* __restrict__ ovf, float* __restrict__ out) {
    int n = (blockIdx.x * blockDim.x + threadIdx.x) >> 6;
    int lane = threadIdx.x & 63;
    if (n >= N_NODES) return;

    int dg3[3], e3[3];
    #pragma unroll
    for (int r = 0; r < 3; ++r)
        dg3[r] = cur[r * N_NODES + n];
    #pragma unroll
    for (int r = 0; r < 3; ++r) {                     // 3 head-loads in flight together
        int x = r * N_NODES + n;
        e3[r] = (lane < min(dg3[r], SLOTS)) ? (int)eidx[(size_t)x * SLOTS + lane] : 0;
    }

    float o0 = 0.f, o1 = 0.f, o2 = 0.f, o3 = 0.f;
    #pragma unroll
    for (int r = 0; r < 3; ++r) {
        const unsigned short* whl = Wh + r * 256 + lane * 4;
        int deg = dg3[r];
        int m = min(deg, SLOTS);
        int e = e3[r];
        float4 acc = make_float4(0.f, 0.f, 0.f, 0.f);
        int j = 0;
        for (; j + 7 < m; j += 8) {
            int t0 = __shfl(e, j + 0), t1 = __shfl(e, j + 1), t2 = __shfl(e, j + 2), t3 = __shfl(e, j + 3);
            int t4 = __shfl(e, j + 4), t5 = __shfl(e, j + 5), t6 = __shfl(e, j + 6), t7 = __shfl(e, j + 7);
            ushort4 v0 = *(const ushort4*)(whl + (size_t)t0 * N_TOT);
            ushort4 v1 = *(const ushort4*)(whl + (size_t)t1 * N_TOT);
            ushort4 v2 = *(const ushort4*)(whl + (size_t)t2 * N_TOT);
            ushort4 v3 = *(const ushort4*)(whl + (size_t)t3 * N_TOT);
            ushort4 v4 = *(const ushort4*)(whl + (size_t)t4 * N_TOT);
            ushort4 v5 = *(const ushort4*)(whl + (size_t)t5 * N_TOT);
            ushort4 v6 = *(const ushort4*)(whl + (size_t)t6 * N_TOT);
            ushort4 v7 = *(const ushort4*)(whl + (size_t)t7 * N_TOT);
            acc.x += ((bf2f(v0.x) + bf2f(v1.x)) + (bf2f(v2.x) + bf2f(v3.x))) + ((bf2f(v4.x) + bf2f(v5.x)) + (bf2f(v6.x) + bf2f(v7.x)));
            acc.y += ((bf2f(v0.y) + bf2f(v1.y)) + (bf2f(v2.y) + bf2f(v3.y))) + ((bf2f(v4.y) + bf2f(v5.y)) + (bf2f(v6.y) + bf2f(v7.y)));
            acc.z += ((bf2f(v0.z) + bf2f(v1.z)) + (bf2f(v2.z) + bf2f(v3.z))) + ((bf2f(v4.z) + bf2f(v5.z)) + (bf2f(v6.z) + bf2f(v7.z)));
            acc.w += ((bf2f(v0.w) + bf2f(v1.w)) + (bf2f(v2.w) + bf2f(v3.w))) + ((bf2f(v4.w) + bf2f(v5.w)) + (bf2f(v6.w) + bf2f(v7.w)));
        }
        for (; j < m; ++j) {
            int t = __shfl(e, j);
            ushort4 v = *(const ushort4*)(whl + (size_t)t * N_TOT);
            acc.x += bf2f(v.x); acc.y += bf2f(v.y); acc.z += bf2f(v.z); acc.w += bf2f(v.w);
        }
        if (deg > SLOTS) {                            // exact overflow path (cold)
            int x = r * N_NODES + n;
            int nov = min(*ovfc, OVF_CAP);
            for (int i2 = 0; i2 < nov; ++i2) {
                if (ovf[2 * i2] == x) {
                    ushort4 v = *(const ushort4*)(whl + (size_t)ovf[2 * i2 + 1] * N_TOT);
                    acc.x += bf2f(v.x); acc.y += bf2f(v.y); acc.z += bf2f(v.z); acc.w += bf2f(v.w);
                }
            }
        }
        float sc = (deg > 0) ? 1.0f / (float)deg : 0.0f;
        o0 += acc.x * sc; o1 += acc.y * sc; o2 += acc.z * sc; o3 += acc.w * sc;
    }
    f32x4 o;
    o.x = fmaxf(o0, 0.0f); o.y = fmaxf(o1, 0.0f);
    o.z = fmaxf(o2, 0.0f); o.w = fmaxf(o3, 0.0f);
    __builtin_nontemporal_store(o, (f32x4*)(out + (size_t)n * D + lane * 4));
}

extern "C" void kernel_launch(void* const* d_in, const int* in_sizes, int n_in,
                              void* d_out, int out_size, void* d_ws, size_t ws_size,
                              hipStream_t stream) {
    const float* feat = (const float*)d_in[0];
    const int* src0 = (const int*)d_in[1];
    const int* dst0 = (const int*)d_in[2];
    const int* src1 = (const int*)d_in[3];
    const int* dst1 = (const int*)d_in[4];
    const int* src2 = (const int*)d_in[5];
    const int* dst2 = (const int*)d_in[6];
    const float* W0 = (const float*)d_in[7];
    const float* b0 = (const float*)d_in[8];
    const float* W1 = (const float*)d_in[9];
    const float* b1 = (const float*)d_in[10];
    const float* W2 = (const float*)d_in[11];
    const float* b2 = (const float*)d_in[12];
    float* out = (float*)d_out;

    char* ws = (char*)d_ws;
    size_t o = 0;
    auto alloc = [&](size_t bytes) {
        size_t r = o;
        o += (bytes + 255) & ~(size_t)255;
        return r;
    };
    int* cur            = (int*)(ws + alloc((size_t)SCAN_N * 4));
    int* ovfc           = (int*)(ws + alloc(4 + (size_t)OVF_CAP * 8));
    int* ovf            = ovfc + 1;
    unsigned short* eidx = (unsigned short*)(ws + alloc((size_t)SCAN_N * SLOTS * 2));
    unsigned short* WT  = (unsigned short*)(ws + alloc((size_t)N_TOT * D * 2));
    unsigned short* fb  = (unsigned short*)(ws + alloc((size_t)N_NODES * D * 2));
    unsigned short* Wh  = (unsigned short*)(ws + alloc((size_t)N_NODES * N_TOT * 2));

    (void)hipMemsetAsync(cur, 0, (size_t)SCAN_N * 4 + 256, stream);  // cur + ovfc
    prep_kernel<<<(N_NODES * D / 4 + 255) / 256, 256, 0, stream>>>(feat, fb, W0, W1, W2, WT);
    dim3 gg(NMB, 3);
    gemm_kernel<<<gg, 768, 0, stream>>>(fb, WT, b0, b1, b2, Wh,
                                        src0, dst0, src1, dst1, src2, dst2,
                                        cur, eidx, ovfc, ovf);
    agg_kernel<<<(N_NODES * 64 + 255) / 256, 256, 0, stream>>>(Wh, cur, eidx, ovfc, ovf, out);
}

// Round 19
// 222.561 us; speedup vs baseline: 1.6093x; 1.1160x over previous
//
#include <hip/hip_runtime.h>
#include <hip/hip_bf16.h>

#define N_NODES 50000
#define N_EDGES 500000
#define D 256
#define N_TOT 768      // 3 * D output cols of Wh
#define SCAN_N (3 * N_NODES)
#define NMB ((N_NODES + 255) / 256)          // 196 M-blocks
#define GBLK (NMB * 3)                       // 588 gemm blocks
#define FBLK (GBLK * 2)                      // 1176 fill blocks
#define TBLK (GBLK * 3)                      // 1764 total, interleaved 1 gemm : 2 fill
#define JOBS (3 * N_EDGES)                   // 1.5M fill jobs
#define SLOTS 32                             // 32 x u16 = 64 B = ONE cache line per (r,node)
#define OVF_CAP 2048

typedef __attribute__((ext_vector_type(8))) __bf16 bf16x8;
typedef __attribute__((ext_vector_type(4))) float f32x4;

__device__ __forceinline__ unsigned short f2bf(float f) {
    unsigned u = __builtin_bit_cast(unsigned, f);
    u += 0x7FFFu + ((u >> 16) & 1u);   // round-to-nearest-even
    return (unsigned short)(u >> 16);
}
__device__ __forceinline__ float bf2f(unsigned short h) {
    return __builtin_bit_cast(float, (unsigned)h << 16);
}
__device__ __forceinline__ void gload16(const unsigned short* g, __bf16* l) {
    __builtin_amdgcn_global_load_lds(
        (const __attribute__((address_space(1))) void*)g,
        (__attribute__((address_space(3))) void*)l, 16, 0, 0);
}

// ---------------- prep: feat->bf16 + W->bf16 transposed (pure streaming) ----------------
// WT layout: [768 outcols j=r*256+c][256 k], WT[j][k] = W_r[k][c]
__global__ void prep_kernel(const float* __restrict__ feat, unsigned short* __restrict__ fb,
                            const float* __restrict__ W0, const float* __restrict__ W1,
                            const float* __restrict__ W2, unsigned short* __restrict__ WT) {
    int i = blockIdx.x * blockDim.x + threadIdx.x;
    if (i < N_NODES * D / 4) {                       // 3.2M float4 slots
        float4 v = ((const float4*)feat)[i];
        ushort4 pk;
        pk.x = f2bf(v.x); pk.y = f2bf(v.y); pk.z = f2bf(v.z); pk.w = f2bf(v.w);
        ((ushort4*)fb)[i] = pk;
    }
    if (i < N_TOT * D) {                             // 196608: WT[j][k] = W_r[k][c]
        int j = i >> 8, k = i & 255;
        int r = j >> 8, c = j & 255;
        const float* W = (r == 0) ? W0 : (r == 1) ? W1 : W2;
        WT[i] = f2bf(W[k * D + c]);
    }
}

// ---------------- fused GEMM + FILL at BLOCK granularity ----------------
// blockIdx.x % 3 == 0 -> gemm block (588, unchanged 512-thread structure, 128 KB LDS).
// else -> fill block (1176, no LDS, no barriers, ~8 VGPR): co-resides on gemm CUs
// (8+8 waves <= 32), HW scheduler interleaves freely -- no barrier lockstep.
// 1:2 dispatch interleave avoids head-of-line blocking of the in-order block queue.
__global__ __launch_bounds__(512) void gemm_kernel(
    const unsigned short* __restrict__ A, const unsigned short* __restrict__ BT,
    const float* __restrict__ b0, const float* __restrict__ b1, const float* __restrict__ b2,
    unsigned short* __restrict__ Wh,
    const int* __restrict__ s0, const int* __restrict__ d0,
    const int* __restrict__ s1, const int* __restrict__ d1,
    const int* __restrict__ s2, const int* __restrict__ d2,
    int* __restrict__ cur, unsigned short* __restrict__ eidx,
    int* __restrict__ ovfc, int* __restrict__ ovf) {
    __shared__ __bf16 Asl[2][256][64];   // 2 x 32 KB (gemm blocks only)
    __shared__ __bf16 Bsl[2][256][64];   // 2 x 32 KB
    int id = blockIdx.x;
    int tid = threadIdx.x;

    if (id % 3 != 0) {
        // ---------------- fill role: grid-stride, independent jobs, full ILP ----------------
        int fid = 2 * (id / 3) + (id % 3) - 1;       // 0..FBLK-1
        for (int j = fid * 512 + tid; j < JOBS; j += FBLK * 512) {
            int r = j / N_EDGES;
            int e = j - r * N_EDGES;
            const int* d = (r == 0) ? d0 : (r == 1) ? d1 : d2;
            const int* s = (r == 0) ? s0 : (r == 1) ? s1 : s2;
            int x = r * N_NODES + d[e];
            int rank = atomicAdd(&cur[x], 1);
            if (rank < SLOTS) {
                eidx[(size_t)x * SLOTS + rank] = (unsigned short)s[e];
            } else {                                 // provably-cold exact overflow
                int op = atomicAdd(ovfc, 1);
                if (op < OVF_CAP) { ovf[2 * op] = x; ovf[2 * op + 1] = s[e]; }
            }
        }
        return;
    }

    // ---------------- gemm role (unchanged structure) ----------------
    int g = id / 3;                      // 0..587
    int lane = tid & 63, w = tid >> 6;   // 8 waves
    int wr = w >> 2, wc = w & 3;         // wave tile: 128 rows x 64 cols
    int m0 = (g % NMB) * 256;
    int p = g / NMB;                     // relation panel 0..2
    const float* bp = (p == 0) ? b0 : (p == 1) ? b1 : b2;
    f32x4 acc[8][4] = {};

    auto stage = [&](int kt, int b) {
        #pragma unroll
        for (int i = 0; i < 4; ++i) {
            int slot = i * 512 + w * 64 + lane;        // 16B slots, wave-contiguous LDS
            int row = slot >> 3, ks = slot & 7;
            int gsl = ks ^ (row & 7);                  // pre-swizzled global k-slot
            int gm = m0 + row; if (gm >= N_NODES) gm = N_NODES - 1;
            gload16(A + (size_t)gm * D + kt * 64 + gsl * 8,
                    &Asl[b][0][0] + (size_t)slot * 8);
            gload16(BT + (size_t)(p * 256 + row) * D + kt * 64 + gsl * 8,
                    &Bsl[b][0][0] + (size_t)slot * 8);
        }
    };

    stage(0, 0);
    int rr = lane & 15, q = lane >> 4;
    #pragma unroll
    for (int kt = 0; kt < 4; ++kt) {
        asm volatile("s_waitcnt vmcnt(0)" ::: "memory");   // buf kt loads landed
        __builtin_amdgcn_s_barrier();
        int b = kt & 1;
        if (kt + 1 < 4) stage(kt + 1, b ^ 1);              // hide under compute below
        #pragma unroll
        for (int kh = 0; kh < 2; ++kh) {                   // two k-halves of BK=64
            bf16x8 af[8], bfr[4];
            #pragma unroll
            for (int mf = 0; mf < 8; ++mf) {
                int row = wr * 128 + mf * 16 + rr;
                int sl = (kh * 4 + q) ^ (row & 7);
                af[mf] = *(const bf16x8*)(&Asl[b][row][0] + sl * 8);
            }
            #pragma unroll
            for (int nf = 0; nf < 4; ++nf) {
                int row = wc * 64 + nf * 16 + rr;
                int sl = (kh * 4 + q) ^ (row & 7);
                bfr[nf] = *(const bf16x8*)(&Bsl[b][row][0] + sl * 8);
            }
            #pragma unroll
            for (int mf = 0; mf < 8; ++mf)
                #pragma unroll
                for (int nf = 0; nf < 4; ++nf)
                    acc[mf][nf] = __builtin_amdgcn_mfma_f32_16x16x32_bf16(af[mf], bfr[nf], acc[mf][nf], 0, 0, 0);
        }
        __builtin_amdgcn_s_barrier();                      // done reading buf b
    }

    // epilogue: +bias, cast bf16; C/D layout: col = lane&15, row = (lane>>4)*4 + reg
    #pragma unroll
    for (int mf = 0; mf < 8; ++mf) {
        #pragma unroll
        for (int nf = 0; nf < 4; ++nf) {
            int col = wc * 64 + nf * 16 + rr;
            float bb = bp[col];
            #pragma unroll
            for (int reg = 0; reg < 4; ++reg) {
                int row = m0 + wr * 128 + mf * 16 + q * 4 + reg;
                if (row < N_NODES)
                    Wh[(size_t)row * N_TOT + p * 256 + col] = f2bf(acc[mf][nf][reg] + bb);
            }
        }
    }
}

// ---------------- final: per-node gather Wh, mean per relation, sum, relu -> out (f32) ----------------
// One wave per node, all 3 relations; lane owns 4 channels (8B loads); 8-deep
// independent gathers. Bias already inside Wh -> deg=0 relations contribute exactly 0.
__global__ void agg_kernel(const unsigned short* __restrict__ Wh, const int* __restrict__ cur,
                           const unsigned short* __restrict__ eidx, const int* __restrict__ ovfc,
                           const int* __restrict__ ovf, float* __restrict__ out) {
    int n = (blockIdx.x * blockDim.x + threadIdx.x) >> 6;
    int lane = threadIdx.x & 63;
    if (n >= N_NODES) return;

    int dg3[3], e3[3];
    #pragma unroll
    for (int r = 0; r < 3; ++r)
        dg3[r] = cur[r * N_NODES + n];
    #pragma unroll
    for (int r = 0; r < 3; ++r) {                     // 3 head-loads in flight together
        int x = r * N_NODES + n;
        e3[r] = (lane < min(dg3[r], SLOTS)) ? (int)eidx[(size_t)x * SLOTS + lane] : 0;
    }

    float o0 = 0.f, o1 = 0.f, o2 = 0.f, o3 = 0.f;
    #pragma unroll
    for (int r = 0; r < 3; ++r) {
        const unsigned short* whl = Wh + r * 256 + lane * 4;
        int deg = dg3[r];
        int m = min(deg, SLOTS);
        int e = e3[r];
        float4 acc = make_float4(0.f, 0.f, 0.f, 0.f);
        int j = 0;
        for (; j + 7 < m; j += 8) {
            int t0 = __shfl(e, j + 0), t1 = __shfl(e, j + 1), t2 = __shfl(e, j + 2), t3 = __shfl(e, j + 3);
            int t4 = __shfl(e, j + 4), t5 = __shfl(e, j + 5), t6 = __shfl(e, j + 6), t7 = __shfl(e, j + 7);
            ushort4 v0 = *(const ushort4*)(whl + (size_t)t0 * N_TOT);
            ushort4 v1 = *(const ushort4*)(whl + (size_t)t1 * N_TOT);
            ushort4 v2 = *(const ushort4*)(whl + (size_t)t2 * N_TOT);
            ushort4 v3 = *(const ushort4*)(whl + (size_t)t3 * N_TOT);
            ushort4 v4 = *(const ushort4*)(whl + (size_t)t4 * N_TOT);
            ushort4 v5 = *(const ushort4*)(whl + (size_t)t5 * N_TOT);
            ushort4 v6 = *(const ushort4*)(whl + (size_t)t6 * N_TOT);
            ushort4 v7 = *(const ushort4*)(whl + (size_t)t7 * N_TOT);
            acc.x += ((bf2f(v0.x) + bf2f(v1.x)) + (bf2f(v2.x) + bf2f(v3.x))) + ((bf2f(v4.x) + bf2f(v5.x)) + (bf2f(v6.x) + bf2f(v7.x)));
            acc.y += ((bf2f(v0.y) + bf2f(v1.y)) + (bf2f(v2.y) + bf2f(v3.y))) + ((bf2f(v4.y) + bf2f(v5.y)) + (bf2f(v6.y) + bf2f(v7.y)));
            acc.z += ((bf2f(v0.z) + bf2f(v1.z)) + (bf2f(v2.z) + bf2f(v3.z))) + ((bf2f(v4.z) + bf2f(v5.z)) + (bf2f(v6.z) + bf2f(v7.z)));
            acc.w += ((bf2f(v0.w) + bf2f(v1.w)) + (bf2f(v2.w) + bf2f(v3.w))) + ((bf2f(v4.w) + bf2f(v5.w)) + (bf2f(v6.w) + bf2f(v7.w)));
        }
        for (; j < m; ++j) {
            int t = __shfl(e, j);
            ushort4 v = *(const ushort4*)(whl + (size_t)t * N_TOT);
            acc.x += bf2f(v.x); acc.y += bf2f(v.y); acc.z += bf2f(v.z); acc.w += bf2f(v.w);
        }
        if (deg > SLOTS) {                            // exact overflow path (cold)
            int x = r * N_NODES + n;
            int nov = min(*ovfc, OVF_CAP);
            for (int i2 = 0; i2 < nov; ++i2) {
                if (ovf[2 * i2] == x) {
                    ushort4 v = *(const ushort4*)(whl + (size_t)ovf[2 * i2 + 1] * N_TOT);
                    acc.x += bf2f(v.x); acc.y += bf2f(v.y); acc.z += bf2f(v.z); acc.w += bf2f(v.w);
                }
            }
        }
        float sc = (deg > 0) ? 1.0f / (float)deg : 0.0f;
        o0 += acc.x * sc; o1 += acc.y * sc; o2 += acc.z * sc; o3 += acc.w * sc;
    }
    f32x4 o;
    o.x = fmaxf(o0, 0.0f); o.y = fmaxf(o1, 0.0f);
    o.z = fmaxf(o2, 0.0f); o.w = fmaxf(o3, 0.0f);
    __builtin_nontemporal_store(o, (f32x4*)(out + (size_t)n * D + lane * 4));
}

extern "C" void kernel_launch(void* const* d_in, const int* in_sizes, int n_in,
                              void* d_out, int out_size, void* d_ws, size_t ws_size,
                              hipStream_t stream) {
    const float* feat = (const float*)d_in[0];
    const int* src0 = (const int*)d_in[1];
    const int* dst0 = (const int*)d_in[2];
    const int* src1 = (const int*)d_in[3];
    const int* dst1 = (const int*)d_in[4];
    const int* src2 = (const int*)d_in[5];
    const int* dst2 = (const int*)d_in[6];
    const float* W0 = (const float*)d_in[7];
    const float* b0 = (const float*)d_in[8];
    const float* W1 = (const float*)d_in[9];
    const float* b1 = (const float*)d_in[10];
    const float* W2 = (const float*)d_in[11];
    const float* b2 = (const float*)d_in[12];
    float* out = (float*)d_out;

    char* ws = (char*)d_ws;
    size_t o = 0;
    auto alloc = [&](size_t bytes) {
        size_t r = o;
        o += (bytes + 255) & ~(size_t)255;
        return r;
    };
    int* cur            = (int*)(ws + alloc((size_t)SCAN_N * 4));
    int* ovfc           = (int*)(ws + alloc(4 + (size_t)OVF_CAP * 8));
    int* ovf            = ovfc + 1;
    unsigned short* eidx = (unsigned short*)(ws + alloc((size_t)SCAN_N * SLOTS * 2));
    unsigned short* WT  = (unsigned short*)(ws + alloc((size_t)N_TOT * D * 2));
    unsigned short* fb  = (unsigned short*)(ws + alloc((size_t)N_NODES * D * 2));
    unsigned short* Wh  = (unsigned short*)(ws + alloc((size_t)N_NODES * N_TOT * 2));

    (void)hipMemsetAsync(cur, 0, (size_t)SCAN_N * 4 + 256, stream);  // cur + ovfc
    prep_kernel<<<(N_NODES * D / 4 + 255) / 256, 256, 0, stream>>>(feat, fb, W0, W1, W2, WT);
    gemm_kernel<<<TBLK, 512, 0, stream>>>(fb, WT, b0, b1, b2, Wh,
                                          src0, dst0, src1, dst1, src2, dst2,
                                          cur, eidx, ovfc, ovf);
    agg_kernel<<<(N_NODES * 64 + 255) / 256, 256, 0, stream>>>(Wh, cur, eidx, ovfc, ovf, out);
}

// Round 21
// 217.235 us; speedup vs baseline: 1.6487x; 1.0245x over previous
//
#include <hip/hip_runtime.h>
#include <hip/hip_bf16.h>

#define N_NODES 50000
#define N_EDGES 500000
#define D 256
#define N_TOT 768      // 3 * D output cols of Wh
#define SCAN_N (3 * N_NODES)
#define NMB ((N_NODES + 255) / 256)          // 196 M-blocks
#define GBLK (NMB * 3)                       // 588 gemm blocks
#define FBLK (GBLK * 2)                      // 1176 fill blocks
#define TBLK (GBLK * 3)                      // 1764 total, interleaved 1 gemm : 2 fill
#define JOBS (3 * N_EDGES)                   // 1.5M fill jobs
#define SLOTS 32                             // 32 x u16 = 64 B = ONE cache line per (r,node)
#define OVF_CAP 2048

typedef __attribute__((ext_vector_type(8))) __bf16 bf16x8;
typedef __attribute__((ext_vector_type(4))) float f32x4;

__device__ __forceinline__ unsigned short f2bf(float f) {
    unsigned u = __builtin_bit_cast(unsigned, f);
    u += 0x7FFFu + ((u >> 16) & 1u);   // round-to-nearest-even
    return (unsigned short)(u >> 16);
}
__device__ __forceinline__ float bf2f(unsigned short h) {
    return __builtin_bit_cast(float, (unsigned)h << 16);
}
__device__ __forceinline__ void gload16(const unsigned short* g, __bf16* l) {
    __builtin_amdgcn_global_load_lds(
        (const __attribute__((address_space(1))) void*)g,
        (__attribute__((address_space(3))) void*)l, 16, 0, 0);
}

// ---------------- prep: feat->bf16 + W->bf16 transposed + zero cur/ovfc ----------------
// (cur zeroing folded in: kernel-boundary coherence publishes zeros to the fused
//  kernel's atomics; removes the separate memset dispatch + gap)
// WT layout: [768 outcols j=r*256+c][256 k], WT[j][k] = W_r[k][c]
__global__ void prep_kernel(const float* __restrict__ feat, unsigned short* __restrict__ fb,
                            const float* __restrict__ W0, const float* __restrict__ W1,
                            const float* __restrict__ W2, unsigned short* __restrict__ WT,
                            int* __restrict__ cur, int* __restrict__ ovfc) {
    int i = blockIdx.x * blockDim.x + threadIdx.x;
    if (i < N_NODES * D / 4) {                       // 3.2M float4 slots
        float4 v = ((const float4*)feat)[i];
        ushort4 pk;
        pk.x = f2bf(v.x); pk.y = f2bf(v.y); pk.z = f2bf(v.z); pk.w = f2bf(v.w);
        ((ushort4*)fb)[i] = pk;
    }
    if (i < N_TOT * D) {                             // 196608: WT[j][k] = W_r[k][c]
        int j = i >> 8, k = i & 255;
        int r = j >> 8, c = j & 255;
        const float* W = (r == 0) ? W0 : (r == 1) ? W1 : W2;
        WT[i] = f2bf(W[k * D + c]);
    }
    if (i < SCAN_N) cur[i] = 0;                      // zero bucket counters
    if (i == 0) *ovfc = 0;
}

// ---------------- fused GEMM + FILL at BLOCK granularity (r19-proven) ----------------
// blockIdx.x % 3 == 0 -> gemm block (588, 512-thread, 128 KB LDS, 2-buffer BK=64,
//   vmcnt(0)+s_barrier top / s_barrier bottom per K-step, gload16 staging).
// else -> fill block (1176, no LDS, no barriers): bucket-CSR scatter, co-resident on
//   gemm CUs, HW-interleaved. 1:2 dispatch interleave avoids head-of-line blocking.
__global__ __launch_bounds__(512) void gemm_kernel(
    const unsigned short* __restrict__ A, const unsigned short* __restrict__ BT,
    const float* __restrict__ b0, const float* __restrict__ b1, const float* __restrict__ b2,
    unsigned short* __restrict__ Wh,
    const int* __restrict__ s0, const int* __restrict__ d0,
    const int* __restrict__ s1, const int* __restrict__ d1,
    const int* __restrict__ s2, const int* __restrict__ d2,
    int* __restrict__ cur, unsigned short* __restrict__ eidx,
    int* __restrict__ ovfc, int* __restrict__ ovf) {
    __shared__ __bf16 Asl[2][256][64];   // 2 x 32 KB (gemm blocks only)
    __shared__ __bf16 Bsl[2][256][64];   // 2 x 32 KB
    int id = blockIdx.x;
    int tid = threadIdx.x;

    if (id % 3 != 0) {
        // ---------------- fill role: grid-stride, independent jobs, full ILP ----------------
        int fid = 2 * (id / 3) + (id % 3) - 1;       // 0..FBLK-1
        for (int j = fid * 512 + tid; j < JOBS; j += FBLK * 512) {
            int r = j / N_EDGES;
            int e = j - r * N_EDGES;
            const int* d = (r == 0) ? d0 : (r == 1) ? d1 : d2;
            const int* s = (r == 0) ? s0 : (r == 1) ? s1 : s2;
            int x = r * N_NODES + d[e];
            int rank = atomicAdd(&cur[x], 1);
            if (rank < SLOTS) {
                eidx[(size_t)x * SLOTS + rank] = (unsigned short)s[e];
            } else {                                 // provably-cold exact overflow
                int op = atomicAdd(ovfc, 1);
                if (op < OVF_CAP) { ovf[2 * op] = x; ovf[2 * op + 1] = s[e]; }
            }
        }
        return;
    }

    // ---------------- gemm role (r19 structure, verbatim) ----------------
    int g = id / 3;                      // 0..587
    int lane = tid & 63, w = tid >> 6;   // 8 waves
    int wr = w >> 2, wc = w & 3;         // wave tile: 128 rows x 64 cols
    int m0 = (g % NMB) * 256;
    int p = g / NMB;                     // relation panel 0..2
    const float* bp = (p == 0) ? b0 : (p == 1) ? b1 : b2;
    f32x4 acc[8][4] = {};

    auto stage = [&](int kt, int b) {
        #pragma unroll
        for (int i = 0; i < 4; ++i) {
            int slot = i * 512 + w * 64 + lane;        // 16B slots, wave-contiguous LDS
            int row = slot >> 3, ks = slot & 7;
            int gsl = ks ^ (row & 7);                  // pre-swizzled global k-slot
            int gm = m0 + row; if (gm >= N_NODES) gm = N_NODES - 1;
            gload16(A + (size_t)gm * D + kt * 64 + gsl * 8,
                    &Asl[b][0][0] + (size_t)slot * 8);
            gload16(BT + (size_t)(p * 256 + row) * D + kt * 64 + gsl * 8,
                    &Bsl[b][0][0] + (size_t)slot * 8);
        }
    };

    stage(0, 0);
    int rr = lane & 15, q = lane >> 4;
    #pragma unroll
    for (int kt = 0; kt < 4; ++kt) {
        asm volatile("s_waitcnt vmcnt(0)" ::: "memory");   // buf kt loads landed
        __builtin_amdgcn_s_barrier();
        int b = kt & 1;
        if (kt + 1 < 4) stage(kt + 1, b ^ 1);              // hide under compute below
        #pragma unroll
        for (int kh = 0; kh < 2; ++kh) {                   // two k-halves of BK=64
            bf16x8 af[8], bfr[4];
            #pragma unroll
            for (int mf = 0; mf < 8; ++mf) {
                int row = wr * 128 + mf * 16 + rr;
                int sl = (kh * 4 + q) ^ (row & 7);
                af[mf] = *(const bf16x8*)(&Asl[b][row][0] + sl * 8);
            }
            #pragma unroll
            for (int nf = 0; nf < 4; ++nf) {
                int row = wc * 64 + nf * 16 + rr;
                int sl = (kh * 4 + q) ^ (row & 7);
                bfr[nf] = *(const bf16x8*)(&Bsl[b][row][0] + sl * 8);
            }
            #pragma unroll
            for (int mf = 0; mf < 8; ++mf)
                #pragma unroll
                for (int nf = 0; nf < 4; ++nf)
                    acc[mf][nf] = __builtin_amdgcn_mfma_f32_16x16x32_bf16(af[mf], bfr[nf], acc[mf][nf], 0, 0, 0);
        }
        __builtin_amdgcn_s_barrier();                      // done reading buf b
    }

    // epilogue: +bias, cast bf16; C/D layout: col = lane&15, row = (lane>>4)*4 + reg
    #pragma unroll
    for (int mf = 0; mf < 8; ++mf) {
        #pragma unroll
        for (int nf = 0; nf < 4; ++nf) {
            int col = wc * 64 + nf * 16 + rr;
            float bb = bp[col];
            #pragma unroll
            for (int reg = 0; reg < 4; ++reg) {
                int row = m0 + wr * 128 + mf * 16 + q * 4 + reg;
                if (row < N_NODES)
                    Wh[(size_t)row * N_TOT + p * 256 + col] = f2bf(acc[mf][nf][reg] + bb);
            }
        }
    }
}

// ---------------- final: per-node gather Wh, mean per relation, sum, relu -> out (f32) ----------------
// One wave per node, all 3 relations; lane owns 4 channels (8B loads); 8-deep
// independent gathers. Bias already inside Wh -> deg=0 relations contribute exactly 0.
__global__ void agg_kernel(const unsigned short* __restrict__ Wh, const int* __restrict__ cur,
                           const unsigned short* __restrict__ eidx, const int* __restrict__ ovfc,
                           const int* __restrict__ ovf, float* __restrict__ out) {
    int n = (blockIdx.x * blockDim.x + threadIdx.x) >> 6;
    int lane = threadIdx.x & 63;
    if (n >= N_NODES) return;

    int dg3[3], e3[3];
    #pragma unroll
    for (int r = 0; r < 3; ++r)
        dg3[r] = cur[r * N_NODES + n];
    #pragma unroll
    for (int r = 0; r < 3; ++r) {                     // 3 head-loads in flight together
        int x = r * N_NODES + n;
        e3[r] = (lane < min(dg3[r], SLOTS)) ? (int)eidx[(size_t)x * SLOTS + lane] : 0;
    }

    float o0 = 0.f, o1 = 0.f, o2 = 0.f, o3 = 0.f;
    #pragma unroll
    for (int r = 0; r < 3; ++r) {
        const unsigned short* whl = Wh + r * 256 + lane * 4;
        int deg = dg3[r];
        int m = min(deg, SLOTS);
        int e = e3[r];
        float4 acc = make_float4(0.f, 0.f, 0.f, 0.f);
        int j = 0;
        for (; j + 7 < m; j += 8) {
            int t0 = __shfl(e, j + 0), t1 = __shfl(e, j + 1), t2 = __shfl(e, j + 2), t3 = __shfl(e, j + 3);
            int t4 = __shfl(e, j + 4), t5 = __shfl(e, j + 5), t6 = __shfl(e, j + 6), t7 = __shfl(e, j + 7);
            ushort4 v0 = *(const ushort4*)(whl + (size_t)t0 * N_TOT);
            ushort4 v1 = *(const ushort4*)(whl + (size_t)t1 * N_TOT);
            ushort4 v2 = *(const ushort4*)(whl + (size_t)t2 * N_TOT);
            ushort4 v3 = *(const ushort4*)(whl + (size_t)t3 * N_TOT);
            ushort4 v4 = *(const ushort4*)(whl + (size_t)t4 * N_TOT);
            ushort4 v5 = *(const ushort4*)(whl + (size_t)t5 * N_TOT);
            ushort4 v6 = *(const ushort4*)(whl + (size_t)t6 * N_TOT);
            ushort4 v7 = *(const ushort4*)(whl + (size_t)t7 * N_TOT);
            acc.x += ((bf2f(v0.x) + bf2f(v1.x)) + (bf2f(v2.x) + bf2f(v3.x))) + ((bf2f(v4.x) + bf2f(v5.x)) + (bf2f(v6.x) + bf2f(v7.x)));
            acc.y += ((bf2f(v0.y) + bf2f(v1.y)) + (bf2f(v2.y) + bf2f(v3.y))) + ((bf2f(v4.y) + bf2f(v5.y)) + (bf2f(v6.y) + bf2f(v7.y)));
            acc.z += ((bf2f(v0.z) + bf2f(v1.z)) + (bf2f(v2.z) + bf2f(v3.z))) + ((bf2f(v4.z) + bf2f(v5.z)) + (bf2f(v6.z) + bf2f(v7.z)));
            acc.w += ((bf2f(v0.w) + bf2f(v1.w)) + (bf2f(v2.w) + bf2f(v3.w))) + ((bf2f(v4.w) + bf2f(v5.w)) + (bf2f(v6.w) + bf2f(v7.w)));
        }
        for (; j < m; ++j) {
            int t = __shfl(e, j);
            ushort4 v = *(const ushort4*)(whl + (size_t)t * N_TOT);
            acc.x += bf2f(v.x); acc.y += bf2f(v.y); acc.z += bf2f(v.z); acc.w += bf2f(v.w);
        }
        if (deg > SLOTS) {                            // exact overflow path (cold)
            int x = r * N_NODES + n;
            int nov = min(*ovfc, OVF_CAP);
            for (int i2 = 0; i2 < nov; ++i2) {
                if (ovf[2 * i2] == x) {
                    ushort4 v = *(const ushort4*)(whl + (size_t)ovf[2 * i2 + 1] * N_TOT);
                    acc.x += bf2f(v.x); acc.y += bf2f(v.y); acc.z += bf2f(v.z); acc.w += bf2f(v.w);
                }
            }
        }
        float sc = (deg > 0) ? 1.0f / (float)deg : 0.0f;
        o0 += acc.x * sc; o1 += acc.y * sc; o2 += acc.z * sc; o3 += acc.w * sc;
    }
    f32x4 o;
    o.x = fmaxf(o0, 0.0f); o.y = fmaxf(o1, 0.0f);
    o.z = fmaxf(o2, 0.0f); o.w = fmaxf(o3, 0.0f);
    __builtin_nontemporal_store(o, (f32x4*)(out + (size_t)n * D + lane * 4));
}

extern "C" void kernel_launch(void* const* d_in, const int* in_sizes, int n_in,
                              void* d_out, int out_size, void* d_ws, size_t ws_size,
                              hipStream_t stream) {
    const float* feat = (const float*)d_in[0];
    const int* src0 = (const int*)d_in[1];
    const int* dst0 = (const int*)d_in[2];
    const int* src1 = (const int*)d_in[3];
    const int* dst1 = (const int*)d_in[4];
    const int* src2 = (const int*)d_in[5];
    const int* dst2 = (const int*)d_in[6];
    const float* W0 = (const float*)d_in[7];
    const float* b0 = (const float*)d_in[8];
    const float* W1 = (const float*)d_in[9];
    const float* b1 = (const float*)d_in[10];
    const float* W2 = (const float*)d_in[11];
    const float* b2 = (const float*)d_in[12];
    float* out = (float*)d_out;

    char* ws = (char*)d_ws;
    size_t o = 0;
    auto alloc = [&](size_t bytes) {
        size_t r = o;
        o += (bytes + 255) & ~(size_t)255;
        return r;
    };
    int* cur            = (int*)(ws + alloc((size_t)SCAN_N * 4));
    int* ovfc           = (int*)(ws + alloc(4 + (size_t)OVF_CAP * 8));
    int* ovf            = ovfc + 1;
    unsigned short* eidx = (unsigned short*)(ws + alloc((size_t)SCAN_N * SLOTS * 2));
    unsigned short* WT  = (unsigned short*)(ws + alloc((size_t)N_TOT * D * 2));
    unsigned short* fb  = (unsigned short*)(ws + alloc((size_t)N_NODES * D * 2));
    unsigned short* Wh  = (unsigned short*)(ws + alloc((size_t)N_NODES * N_TOT * 2));

    prep_kernel<<<(N_NODES * D / 4 + 255) / 256, 256, 0, stream>>>(
        feat, fb, W0, W1, W2, WT, cur, ovfc);
    gemm_kernel<<<TBLK, 512, 0, stream>>>(fb, WT, b0, b1, b2, Wh,
                                          src0, dst0, src1, dst1, src2, dst2,
                                          cur, eidx, ovfc, ovf);
    agg_kernel<<<(N_NODES * 64 + 255) / 256, 256, 0, stream>>>(Wh, cur, eidx, ovfc, ovf, out);
}